// Round 1
// 405.495 us; speedup vs baseline: 1.0249x; 1.0249x over previous
//
#include <hip/hip_runtime.h>
#include <hip/hip_bf16.h>

// B=8, T=2048, E=1024, D=DK*H=1024 (heads fused in reference math)
//   QKV = x @ [Wq|Wk|Wv]  fused GEMM  [16384 x 3072] bf16 (V stored transposed);
//         m-blocks entirely beyond len[b] skip compute and store zeros.
//   energy[b] = Q_b K_b^T  fp16; n-blocks bn>=len skipped; NEW: m-blocks
//         bm>=len store exact zeros (Q rows are zero) without compute.
//   lengths[b] = #nonzero rows of x[b]
//   P = softmax(mask(energy)/8) bf16 in place over fp16 rows (one row per wave)
//   out[b] = P_b V_b  fp32; K-loop clamped to round64(len[b]).
//
// R9: GEMM ported from m97 128x128/BK32 2-phase (25% MfmaUtil, 1e7 LDS bank
// conflicts, vmcnt(0)-drain per K-step) to the 256x256/BK64 8-phase template:
//   - 512 thr = 8 waves (2M x 4N), per-wave C = 128x64, acc[8][4] f32x4
//   - LDS 128 KiB: A,B double-buffered [2][256][64] bf16
//   - per K-tile 4 phases, each {ds_read subtile | stage-issue} BAR {MFMA} BAR
//     with sched_barrier(0) pinning; setprio(1) around MFMA clusters (T5)
//   - counted s_waitcnt vmcnt(8) ONCE per K-tile (T4); stage for tile t+2 is
//     issued in P4 of tile t, i.e. after the P3-closing barrier proves all
//     waves finished reading buf[t&1]  (write-after-read safe)
//   - XOR swizzle byte^=(row&7)<<4 (T2): applied to the per-lane GLOBAL source
//     of global_load_lds (LDS dest stays linear, rule #21) and to the
//     ds_read_b128 address -> conflict-free fragment reads
// ws = 140,509,440 B: lengths 256B | x16 32MB | WT 6MB | VT 32MB | E 64MB fp16.

typedef unsigned short u16;
typedef __bf16 bf16x8 __attribute__((ext_vector_type(8)));
typedef float f32x4 __attribute__((ext_vector_type(4)));
typedef unsigned short us8 __attribute__((ext_vector_type(8)));

__device__ __forceinline__ u16 f2bf(float f) {
    union { float f; unsigned u; } x; x.f = f;
    unsigned r = x.u + 0x7FFFu + ((x.u >> 16) & 1u);   // RNE
    return (u16)(r >> 16);
}
__device__ __forceinline__ u16 f2h(float f) {
    union { _Float16 h; u16 u; } c; c.h = (_Float16)f;
    return c.u;
}
__device__ __forceinline__ float h2f(u16 b) {
    union { u16 u; _Float16 h; } c; c.u = b;
    return (float)c.h;
}

__device__ __forceinline__ void gload_lds16(const void* g, void* l) {
    __builtin_amdgcn_global_load_lds(
        (const __attribute__((address_space(1))) unsigned*)g,
        (__attribute__((address_space(3))) unsigned*)l, 16, 0, 0);
}

// ---------------------------------------------------------------- cast x -> bf16
__global__ void cast_x(const float* __restrict__ x, u16* __restrict__ o) {
    int i = blockIdx.x * 256 + threadIdx.x;          // float4 index
    float4 v = ((const float4*)x)[i];
    ushort4 u;
    u.x = f2bf(v.x); u.y = f2bf(v.y); u.z = f2bf(v.z); u.w = f2bf(v.w);
    ((ushort4*)o)[i] = u;
}

// ------------------------------------------------- W[e][n] -> WT[n][e] bf16, x3
__global__ void transpose_cast_w(const float* __restrict__ Wq,
                                 const float* __restrict__ Wk,
                                 const float* __restrict__ Wv,
                                 u16* __restrict__ WT) {
    __shared__ float tile[32][33];
    const float* W = (blockIdx.z == 0) ? Wq : (blockIdx.z == 1) ? Wk : Wv;
    u16* T = WT + (size_t)blockIdx.z * 1048576;
    int n0 = blockIdx.x * 32, e0 = blockIdx.y * 32;
    int tx = threadIdx.x, ty = threadIdx.y;
#pragma unroll
    for (int j = 0; j < 4; ++j) {
        int e = ty + j * 8;
        tile[e][tx] = W[(size_t)(e0 + e) * 1024 + (n0 + tx)];
    }
    __syncthreads();
#pragma unroll
    for (int j = 0; j < 4; ++j) {
        int n = ty + j * 8;
        T[(size_t)(n0 + n) * 1024 + (e0 + tx)] = f2bf(tile[tx][n]);
    }
}

// ----------------------------------------------------- lengths[b] from x rows
__global__ void calc_lengths(const float* __restrict__ x, int* __restrict__ len) {
    int b = blockIdx.x, tid = threadIdx.x;
    int cnt = 0;
    for (int t = tid; t < 2048; t += 256) {
        float4 v = *(const float4*)(x + ((size_t)b * 2048 + t) * 1024);
        cnt += (v.x != 0.f || v.y != 0.f || v.z != 0.f || v.w != 0.f) ? 1 : 0;
    }
#pragma unroll
    for (int off = 32; off; off >>= 1) cnt += __shfl_xor(cnt, off);
    __shared__ int red[4];
    int wid = tid >> 6, lane = tid & 63;
    if (!lane) red[wid] = cnt;
    __syncthreads();
    if (tid == 0) len[b] = red[0] + red[1] + red[2] + red[3];
}

// ------------------------------------------------------------- bf16 NT GEMM
// 256x256 tile, BK=64, 8-phase pipelined (see header). C[m,n]=sum_k A[m,k]B[n,k].
// MODE 3: fused-QKV routing (y 0-3 Q, 4-7 K, 8-11 V transposed into Cv2)
// MODE 4: energy fp16; n-blocks bn>=len return; m-blocks bm>=len store zeros
// MODE 5: PV fp32; K clamped to round64(len)

#define PHASE_SEP do { __builtin_amdgcn_sched_barrier(0); \
                       __builtin_amdgcn_s_barrier(); \
                       __builtin_amdgcn_sched_barrier(0); } while (0)

#define STAGE_T(KT, BUF) do { \
  _Pragma("unroll") for (int j_ = 0; j_ < 4; ++j_) \
      gload_lds16(A + offA[j_] + (size_t)(KT) * 64, &As[BUF][ldsC[j_]]); \
  _Pragma("unroll") for (int j_ = 0; j_ < 4; ++j_) \
      gload_lds16(B + offB[j_] + (size_t)(KT) * 64, &Bs[BUF][ldsC[j_]]); \
} while (0)

// fragment reads: row*64 u16 per row (128B); 16B chunk index swizzled by row&7
#define LD_A4(AF, BUF, MH) do { \
  _Pragma("unroll") for (int s_ = 0; s_ < 2; ++s_) \
  _Pragma("unroll") for (int mt_ = 0; mt_ < 4; ++mt_) { \
    int row_ = arow0 + (MH) * 64 + mt_ * 16 + r; \
    AF[s_][mt_] = *(const bf16x8*)&As[BUF][row_ * 64 + (((q + s_ * 4) ^ (row_ & 7)) * 8)]; \
  } \
} while (0)

#define LD_B2(BF, BUF, NH) do { \
  _Pragma("unroll") for (int s_ = 0; s_ < 2; ++s_) \
  _Pragma("unroll") for (int nt_ = 0; nt_ < 2; ++nt_) { \
    int row_ = brow0 + (NH) * 32 + nt_ * 16 + r; \
    BF[s_][nt_] = *(const bf16x8*)&Bs[BUF][row_ * 64 + (((q + s_ * 4) ^ (row_ & 7)) * 8)]; \
  } \
} while (0)

#define MFMA_QUAD(AF, BF, MH, NH) do { \
  _Pragma("unroll") for (int s_ = 0; s_ < 2; ++s_) \
  _Pragma("unroll") for (int mt_ = 0; mt_ < 4; ++mt_) \
  _Pragma("unroll") for (int nt_ = 0; nt_ < 2; ++nt_) \
    acc[(MH) * 4 + mt_][(NH) * 2 + nt_] = __builtin_amdgcn_mfma_f32_16x16x32_bf16( \
        AF[s_][mt_], BF[s_][nt_], acc[(MH) * 4 + mt_][(NH) * 2 + nt_], 0, 0, 0); \
} while (0)

template <int MODE>
__global__ __launch_bounds__(512, 2)   // 8 waves, <=256 VGPR, 1 block/CU
void gemm_bt(const u16* __restrict__ A, int lda, size_t sA,
             const u16* __restrict__ B, int ldb, size_t sB,
             void* __restrict__ Cv, void* __restrict__ Cv2,
             int ldc, size_t sC, int Kdim, const int* __restrict__ lenp) {
    __shared__ u16 As[2][256 * 64];    // 64 KiB
    __shared__ u16 Bs[2][256 * 64];    // 64 KiB
    const int tid = threadIdx.x;
    const int bz  = blockIdx.z;
    A += (size_t)bz * sA;
    B += (size_t)bz * sB;
    const size_t bm = (size_t)blockIdx.x * 256, bn = (size_t)blockIdx.y * 256;

    bool skip = false;
    int kEnd = Kdim;
    if (MODE == 3) {
        int lenz = lenp[bm >> 11];
        skip = ((int)(bm & 2047) >= lenz);           // whole tile rows are zero
    } else if (MODE == 4) {
        int lenz = lenp[bz];
        if ((int)bn >= lenz) return;                 // cols fully masked: unread
        skip = ((int)bm >= lenz);                    // Q rows zero -> energy 0
    } else if (MODE == 5) {
        int lenz = lenp[bz];
        int r64 = (lenz + 63) & ~63;
        kEnd = r64 < Kdim ? r64 : Kdim;              // P cols >= len are zeros
    }

    const int wid = tid >> 6, lane = tid & 63;
    const int wm = wid >> 2, wn = wid & 3;           // 2M x 4N wave grid
    const int q = lane >> 4, r = lane & 15;
    const int arow0 = wm * 128, brow0 = wn * 64;

    // staging: each matrix tile = 2048 x 16B chunks; thread owns c = j*512+tid.
    // chunk c -> linear LDS byte c*16 (wave-contiguous: base + lane*16);
    // global source column pre-swizzled so LDS[linear] == swizzled layout.
    size_t offA[4], offB[4]; int ldsC[4];
#pragma unroll
    for (int j = 0; j < 4; ++j) {
        int c = j * 512 + tid;
        int row = c >> 3;
        int c16 = (c & 7) ^ (row & 7);               // inverse(=same) swizzle
        offA[j] = (size_t)(bm + row) * lda + c16 * 8;
        offB[j] = (size_t)(bn + row) * ldb + c16 * 8;
        ldsC[j] = c * 8;
    }

    f32x4 acc[8][4] = {};

    if (!skip) {
        const int NT = kEnd >> 6;                    // >= 16 always (len>=1024)
        STAGE_T(0, 0);
        STAGE_T(1, 1);
        asm volatile("s_waitcnt vmcnt(8)" ::: "memory");   // tile 0 landed
        PHASE_SEP;
        for (int t = 0; t < NT; ++t) {
            const int p = t & 1;
            bf16x8 a[2][4], b0[2][2], b1[2][2];
            // P1: read A(mh0)+B(nh0), compute quad (0,0)
            LD_A4(a, p, 0);
            LD_B2(b0, p, 0);
            PHASE_SEP;
            __builtin_amdgcn_s_setprio(1);
            MFMA_QUAD(a, b0, 0, 0);
            __builtin_amdgcn_s_setprio(0);
            PHASE_SEP;
            // P2: read B(nh1), compute quad (0,1)
            LD_B2(b1, p, 1);
            PHASE_SEP;
            __builtin_amdgcn_s_setprio(1);
            MFMA_QUAD(a, b1, 0, 1);
            __builtin_amdgcn_s_setprio(0);
            PHASE_SEP;
            // P3: read A(mh1), compute quad (1,1).  After this phase's closing
            // barrier every wave has consumed all its reads of buf[p].
            LD_A4(a, p, 1);
            PHASE_SEP;
            __builtin_amdgcn_s_setprio(1);
            MFMA_QUAD(a, b1, 1, 1);
            __builtin_amdgcn_s_setprio(0);
            PHASE_SEP;
            // P4: stage tile t+2 into buf[p] (write-after-read safe), compute
            // quad (1,0) from regs, then counted vmcnt: oldest 8 = tile t+1.
            if (t + 2 < NT) STAGE_T(t + 2, p);
            PHASE_SEP;
            __builtin_amdgcn_s_setprio(1);
            MFMA_QUAD(a, b0, 1, 0);
            __builtin_amdgcn_s_setprio(0);
            __builtin_amdgcn_sched_barrier(0);
            if (t + 2 < NT)      asm volatile("s_waitcnt vmcnt(8)" ::: "memory");
            else if (t + 1 < NT) asm volatile("s_waitcnt vmcnt(0)" ::: "memory");
            __builtin_amdgcn_s_barrier();
            __builtin_amdgcn_sched_barrier(0);
        }
    }

    // C/D layout per 16x16 fragment: col = lane&15, row = (lane>>4)*4 + i
    // acc[am][an]: row = arow0+(am>>2)*64+(am&3)*16+q*4+i,
    //              col = brow0+(an>>1)*32+(an&1)*16+r
    if (MODE == 5) {
        float* C = (float*)Cv + (size_t)bz * sC;
#pragma unroll
        for (int am = 0; am < 8; ++am) {
            size_t row = bm + arow0 + (am >> 2) * 64 + (am & 3) * 16 + q * 4;
#pragma unroll
            for (int an = 0; an < 4; ++an) {
                size_t col = bn + brow0 + (an >> 1) * 32 + (an & 1) * 16 + r;
#pragma unroll
                for (int i = 0; i < 4; ++i)
                    C[(row + i) * (size_t)ldc + col] = acc[am][an][i];
            }
        }
    } else if (MODE == 4) {
        u16* C = (u16*)Cv + (size_t)bz * sC;
#pragma unroll
        for (int am = 0; am < 8; ++am) {
            size_t row = bm + arow0 + (am >> 2) * 64 + (am & 3) * 16 + q * 4;
#pragma unroll
            for (int an = 0; an < 4; ++an) {
                size_t col = bn + brow0 + (an >> 1) * 32 + (an & 1) * 16 + r;
#pragma unroll
                for (int i = 0; i < 4; ++i)
                    C[(row + i) * (size_t)ldc + col] = f2h(acc[am][an][i]);
            }
        }
    } else {  // MODE 3: fused QKV epilogue, region uniform per block
        int region = blockIdx.y >> 2;                 // 0:Q 1:K 2:V
        if (region < 2) {
            u16* C = (u16*)Cv + (size_t)region * 16777216;  // Q or K [16384x1024]
            size_t cb = bn - (size_t)region * 1024;
#pragma unroll
            for (int am = 0; am < 8; ++am) {
                size_t row = bm + arow0 + (am >> 2) * 64 + (am & 3) * 16 + q * 4;
#pragma unroll
                for (int an = 0; an < 4; ++an) {
                    size_t col = cb + brow0 + (an >> 1) * 32 + (an & 1) * 16 + r;
#pragma unroll
                    for (int i = 0; i < 4; ++i)
                        C[(row + i) * 1024 + col] = f2bf(acc[am][an][i]);
                }
            }
        } else {
            // VT[b][d][t] = V[b*2048+t][d]; b = bm>>11 is BLOCK-UNIFORM
            // (256-row tiles never straddle the 2048-row batch boundary).
            // Each lane owns 4 consecutive t at fixed d -> one ushort4 store.
            u16* Cb = (u16*)Cv2 + (bm >> 11) * (size_t)(1024 * 2048)
                      + (bn - 2048) * 2048 + (bm & 2047);
#pragma unroll
            for (int an = 0; an < 4; ++an) {
                int cI = brow0 + (an >> 1) * 32 + (an & 1) * 16 + r;
#pragma unroll
                for (int am = 0; am < 8; ++am) {
                    int tI = arow0 + (am >> 2) * 64 + (am & 3) * 16 + q * 4;
                    ushort4 o;
                    o.x = f2bf(acc[am][an][0]);
                    o.y = f2bf(acc[am][an][1]);
                    o.z = f2bf(acc[am][an][2]);
                    o.w = f2bf(acc[am][an][3]);
                    *(ushort4*)(Cb + (size_t)cI * 2048 + tI) = o;
                }
            }
        }
    }
}

// ---- masked softmax, ONE ROW PER WAVE: fp16 row in, bf16 P in place (full row)
// Read and write both use us8 chunks: chunk c = j*64+lane covers cols c*8..c*8+7.
__global__ void softmax_rows_w(u16* __restrict__ E, const int* __restrict__ lengths) {
    int row  = blockIdx.x * 4 + (threadIdx.x >> 6);   // 16384 rows, 4 waves/block
    int lane = threadIdx.x & 63;
    int len  = lengths[row >> 11];
    u16* e = E + (size_t)row * 2048;

    float vals[32];
#pragma unroll
    for (int j = 0; j < 4; ++j) {
        us8 v = ((const us8*)e)[j * 64 + lane];
#pragma unroll
        for (int w = 0; w < 8; ++w) vals[j * 8 + w] = h2f(v[w]);
    }

    float m = -3.4e38f;
#pragma unroll
    for (int j = 0; j < 4; ++j) {
        int base = (j * 64 + lane) * 8;
#pragma unroll
        for (int w = 0; w < 8; ++w)
            if (base + w < len) m = fmaxf(m, vals[j * 8 + w]);
    }
#pragma unroll
    for (int off = 32; off; off >>= 1) m = fmaxf(m, __shfl_xor(m, off));

    const float C = 0.18033688011112042f;   // log2(e)/8  (scale 1/sqrt(64))
    float p[32]; float s = 0.f;
#pragma unroll
    for (int j = 0; j < 4; ++j) {
        int base = (j * 64 + lane) * 8;
#pragma unroll
        for (int w = 0; w < 8; ++w) {
            float v = (base + w < len) ? exp2f((vals[j * 8 + w] - m) * C) : 0.f;
            p[j * 8 + w] = v;
            s += v;
        }
    }
#pragma unroll
    for (int off = 32; off; off >>= 1) s += __shfl_xor(s, off);
    float rinv = 1.0f / s;

    // bf16 P over the fp16 row, identical chunk mapping as the read
#pragma unroll
    for (int j = 0; j < 4; ++j) {
        us8 o;
#pragma unroll
        for (int w = 0; w < 8; ++w) o[w] = f2bf(p[j * 8 + w] * rinv);
        ((us8*)e)[j * 64 + lane] = o;
    }
}

// ------------------------------------------------------------------ launch
extern "C" void kernel_launch(void* const* d_in, const int* in_sizes, int n_in,
                              void* d_out, int out_size, void* d_ws, size_t ws_size,
                              hipStream_t stream) {
    const float* x  = (const float*)d_in[0];
    const float* Wq = (const float*)d_in[1];
    const float* Wk = (const float*)d_in[2];
    const float* Wv = (const float*)d_in[3];
    float* out = (float*)d_out;
    char* ws = (char*)d_ws;

    const size_t SB  = 2097152;      // u16 elems per batch [2048x1024]
    const size_t SBe = 4194304;      // u16 elems per batch energy [2048x2048]

    // ws: lengths 256B | x16 32MB | WT 6MB | VT 32MB | E 64MB fp16 = 140,509,440 B
    if (ws_size < 140509440ULL) return;
    int* lengths = (int*)ws;
    u16* x16 = (u16*)(ws + 256);
    u16* WT  = (u16*)(ws + 33554688);
    u16* VT  = (u16*)(ws + 39846144);
    u16* E   = (u16*)(ws + 73400576);
    u16* Qb  = (u16*)d_out;                          // Q,K parked in d_out (64 MiB)
    u16* Kb  = Qb + 16777216;

    cast_x<<<dim3(16384), dim3(256), 0, stream>>>(x, x16);
    transpose_cast_w<<<dim3(32, 32, 3), dim3(32, 8), 0, stream>>>(Wq, Wk, Wv, WT);
    calc_lengths<<<dim3(8), dim3(256), 0, stream>>>(x, lengths);

    // fused QKV: x16[16384x1024] @ WT[3072x1024]^T -> Q,K (d_out) + VT (ws)
    gemm_bt<3><<<dim3(64, 12, 1), 512, 0, stream>>>(x16, 1024, 0, WT, 1024, 0,
                                                    Qb, VT, 1024, 0, 1024, lengths);

    // energy[b] = Q_b K_b^T -> fp16 E; bn>=len skipped, bm>=len zero-filled
    gemm_bt<4><<<dim3(8, 8, 8), 512, 0, stream>>>(Qb, 1024, SB, Kb, 1024, SB,
                                                  E, nullptr, 2048, SBe, 1024, lengths);

    // masked softmax -> bf16 P in place (one row per wave)
    softmax_rows_w<<<dim3(4096), dim3(256), 0, stream>>>(E, lengths);

    // out[b] = P_b V_b = P_b (VT_b)^T; K clamped to round64(len[b])
    gemm_bt<5><<<dim3(8, 4, 8), 512, 0, stream>>>(E, 2048, SBe, VT, 2048, SB,
                                                  out, nullptr, 1024, SB, 2048, lengths);
}

// Round 2
// 390.438 us; speedup vs baseline: 1.0645x; 1.0386x over previous
//
#include <hip/hip_runtime.h>
#include <hip/hip_bf16.h>

// B=8, T=2048, E=1024, D=DK*H=1024 (heads fused in reference math)
//   QKV = x @ [Wq|Wk|Wv]  fused GEMM  [16384 x 3072] bf16 (V stored transposed);
//         m-blocks entirely beyond len[b] skip compute and store zeros.
//   energy[b] = Q_b K_b^T  fp16; n-blocks bn>=len skipped; m-blocks bm>=len
//         store exact zeros (Q rows are zero) without compute.
//   lengths[b] = #nonzero rows of x[b]
//   P = softmax(mask(energy)/8) bf16 in place over fp16 rows (one row per wave)
//   out[b] = P_b V_b  fp32; K-loop clamped to round64(len[b]).
//
// R10: R9's 8-phase port only hit MfmaUtil 27% (expected ~60%). Diagnosis:
// fragment ds_reads were plain C++ loads; the compiler cannot disambiguate
// As[p] vs As[p^1] against the global_load_lds LDS-writes, so it inserts
// s_waitcnt vmcnt(0) before every phase's LDS reads -> the counted-vmcnt
// pipeline (T4) is drained every tile and staging serializes with compute
// (~5400 cyc/K-tile vs template's ~1000). Fix (matches m201 exactly):
//   - inline-asm ds_read_b128 on precomputed 32-bit LDS offsets (no alias edge)
//   - explicit s_waitcnt lgkmcnt(0) + sched_barrier(0) before MFMA (rule #18)
//   - manual vmcnt(8) stays the ONLY VMEM wait (once per K-tile)
// WAR safety: all waves' reads of buf[p] are lgkmcnt(0)-drained before P3's
// closing barrier; the stage into buf[p] issues after that barrier.
// ws = 140,509,440 B: lengths 256B | x16 32MB | WT 6MB | VT 32MB | E 64MB fp16.

typedef unsigned short u16;
typedef __bf16 bf16x8 __attribute__((ext_vector_type(8)));
typedef float f32x4 __attribute__((ext_vector_type(4)));
typedef unsigned short us8 __attribute__((ext_vector_type(8)));

__device__ __forceinline__ u16 f2bf(float f) {
    union { float f; unsigned u; } x; x.f = f;
    unsigned r = x.u + 0x7FFFu + ((x.u >> 16) & 1u);   // RNE
    return (u16)(r >> 16);
}
__device__ __forceinline__ u16 f2h(float f) {
    union { _Float16 h; u16 u; } c; c.h = (_Float16)f;
    return c.u;
}
__device__ __forceinline__ float h2f(u16 b) {
    union { u16 u; _Float16 h; } c; c.u = b;
    return (float)c.h;
}

__device__ __forceinline__ void gload_lds16(const void* g, void* l) {
    __builtin_amdgcn_global_load_lds(
        (const __attribute__((address_space(1))) unsigned*)g,
        (__attribute__((address_space(3))) unsigned*)l, 16, 0, 0);
}

// 32-bit LDS byte offset of a __shared__ object (addrspace(3) ptrs are 32-bit)
__device__ __forceinline__ unsigned lds_off(const void* p) {
    return (unsigned)(size_t)(const __attribute__((address_space(3))) char*)p;
}
// opaque LDS read: no alias edge to global_load_lds -> no compiler vmcnt drain
__device__ __forceinline__ bf16x8 ds_read16(unsigned a) {
    bf16x8 r;
    asm volatile("ds_read_b128 %0, %1" : "=v"(r) : "v"(a));
    return r;
}

// ---------------------------------------------------------------- cast x -> bf16
__global__ void cast_x(const float* __restrict__ x, u16* __restrict__ o) {
    int i = blockIdx.x * 256 + threadIdx.x;          // float4 index
    float4 v = ((const float4*)x)[i];
    ushort4 u;
    u.x = f2bf(v.x); u.y = f2bf(v.y); u.z = f2bf(v.z); u.w = f2bf(v.w);
    ((ushort4*)o)[i] = u;
}

// ------------------------------------------------- W[e][n] -> WT[n][e] bf16, x3
__global__ void transpose_cast_w(const float* __restrict__ Wq,
                                 const float* __restrict__ Wk,
                                 const float* __restrict__ Wv,
                                 u16* __restrict__ WT) {
    __shared__ float tile[32][33];
    const float* W = (blockIdx.z == 0) ? Wq : (blockIdx.z == 1) ? Wk : Wv;
    u16* T = WT + (size_t)blockIdx.z * 1048576;
    int n0 = blockIdx.x * 32, e0 = blockIdx.y * 32;
    int tx = threadIdx.x, ty = threadIdx.y;
#pragma unroll
    for (int j = 0; j < 4; ++j) {
        int e = ty + j * 8;
        tile[e][tx] = W[(size_t)(e0 + e) * 1024 + (n0 + tx)];
    }
    __syncthreads();
#pragma unroll
    for (int j = 0; j < 4; ++j) {
        int n = ty + j * 8;
        T[(size_t)(n0 + n) * 1024 + (e0 + tx)] = f2bf(tile[tx][n]);
    }
}

// ----------------------------------------------------- lengths[b] from x rows
__global__ void calc_lengths(const float* __restrict__ x, int* __restrict__ len) {
    int b = blockIdx.x, tid = threadIdx.x;
    int cnt = 0;
    for (int t = tid; t < 2048; t += 256) {
        float4 v = *(const float4*)(x + ((size_t)b * 2048 + t) * 1024);
        cnt += (v.x != 0.f || v.y != 0.f || v.z != 0.f || v.w != 0.f) ? 1 : 0;
    }
#pragma unroll
    for (int off = 32; off; off >>= 1) cnt += __shfl_xor(cnt, off);
    __shared__ int red[4];
    int wid = tid >> 6, lane = tid & 63;
    if (!lane) red[wid] = cnt;
    __syncthreads();
    if (tid == 0) len[b] = red[0] + red[1] + red[2] + red[3];
}

// ------------------------------------------------------------- bf16 NT GEMM
// 256x256 tile, BK=64, 8-phase pipelined. C[m,n]=sum_k A[m,k]B[n,k].
// MODE 3: fused-QKV routing (y 0-3 Q, 4-7 K, 8-11 V transposed into Cv2)
// MODE 4: energy fp16; n-blocks bn>=len return; m-blocks bm>=len store zeros
// MODE 5: PV fp32; K clamped to round64(len)

#define LDS_BAR do { __builtin_amdgcn_sched_barrier(0); \
                     __builtin_amdgcn_s_barrier(); \
                     __builtin_amdgcn_sched_barrier(0); } while (0)

#define WAIT_LGKM do { asm volatile("s_waitcnt lgkmcnt(0)" ::: "memory"); \
                       __builtin_amdgcn_sched_barrier(0); } while (0)

#define STAGE_T(KT, BUF) do { \
  _Pragma("unroll") for (int j_ = 0; j_ < 4; ++j_) \
      gload_lds16(A + offA[j_] + (size_t)(KT) * 64, &As[BUF][ldsC[j_]]); \
  _Pragma("unroll") for (int j_ = 0; j_ < 4; ++j_) \
      gload_lds16(B + offB[j_] + (size_t)(KT) * 64, &Bs[BUF][ldsC[j_]]); \
} while (0)

// fragment reads: precomputed row-base addresses + per-tile parity/swizzle add
#define LD_A4(AF, MH) do { \
  _Pragma("unroll") for (int mt_ = 0; mt_ < 4; ++mt_) { \
    AF[0][mt_] = ds_read16(rowA[(MH) * 4 + mt_] + ps0); \
    AF[1][mt_] = ds_read16(rowA[(MH) * 4 + mt_] + ps1); \
  } \
} while (0)

#define LD_B2(BF, NH) do { \
  _Pragma("unroll") for (int nt_ = 0; nt_ < 2; ++nt_) { \
    BF[0][nt_] = ds_read16(rowB[(NH) * 2 + nt_] + ps0); \
    BF[1][nt_] = ds_read16(rowB[(NH) * 2 + nt_] + ps1); \
  } \
} while (0)

#define MFMA_QUAD(AF, BF, MH, NH) do { \
  _Pragma("unroll") for (int s_ = 0; s_ < 2; ++s_) \
  _Pragma("unroll") for (int mt_ = 0; mt_ < 4; ++mt_) \
  _Pragma("unroll") for (int nt_ = 0; nt_ < 2; ++nt_) \
    acc[(MH) * 4 + mt_][(NH) * 2 + nt_] = __builtin_amdgcn_mfma_f32_16x16x32_bf16( \
        AF[s_][mt_], BF[s_][nt_], acc[(MH) * 4 + mt_][(NH) * 2 + nt_], 0, 0, 0); \
} while (0)

template <int MODE>
__global__ __launch_bounds__(512, 2)   // 8 waves, <=256 unified regs
void gemm_bt(const u16* __restrict__ A, int lda, size_t sA,
             const u16* __restrict__ B, int ldb, size_t sB,
             void* __restrict__ Cv, void* __restrict__ Cv2,
             int ldc, size_t sC, int Kdim, const int* __restrict__ lenp) {
    __shared__ u16 As[2][256 * 64];    // 64 KiB (32 KiB per parity buffer)
    __shared__ u16 Bs[2][256 * 64];    // 64 KiB
    const int tid = threadIdx.x;
    const int bz  = blockIdx.z;
    A += (size_t)bz * sA;
    B += (size_t)bz * sB;
    const size_t bm = (size_t)blockIdx.x * 256, bn = (size_t)blockIdx.y * 256;

    bool skip = false;
    int kEnd = Kdim;
    if (MODE == 3) {
        int lenz = lenp[bm >> 11];
        skip = ((int)(bm & 2047) >= lenz);           // whole tile rows are zero
    } else if (MODE == 4) {
        int lenz = lenp[bz];
        if ((int)bn >= lenz) return;                 // cols fully masked: unread
        skip = ((int)bm >= lenz);                    // Q rows zero -> energy 0
    } else if (MODE == 5) {
        int lenz = lenp[bz];
        int r64 = (lenz + 63) & ~63;
        kEnd = r64 < Kdim ? r64 : Kdim;              // P cols >= len are zeros
    }

    const int wid = tid >> 6, lane = tid & 63;
    const int wm = wid >> 2, wn = wid & 3;           // 2M x 4N wave grid
    const int q = lane >> 4, r = lane & 15;
    const int arow0 = wm * 128, brow0 = wn * 64;

    // staging: each matrix tile = 2048 x 16B chunks; thread owns c = j*512+tid.
    // chunk c -> linear LDS byte c*16 (wave-contiguous: base + lane*16);
    // global source column pre-swizzled so LDS[linear] == swizzled layout.
    size_t offA[4], offB[4]; int ldsC[4];
#pragma unroll
    for (int j = 0; j < 4; ++j) {
        int c = j * 512 + tid;
        int row = c >> 3;
        int c16 = (c & 7) ^ (row & 7);               // inverse(=same) swizzle
        offA[j] = (size_t)(bm + row) * lda + c16 * 8;
        offB[j] = (size_t)(bn + row) * ldb + c16 * 8;
        ldsC[j] = c * 8;
    }

    // precomputed LDS read addresses (buf0): row base + swizzled 16B chunk
    unsigned rowA[8], rowB[4], swz0, swz1;
    {
        unsigned asB = lds_off(&As[0][0]), bsB = lds_off(&Bs[0][0]);
        swz0 = (unsigned)((q ^ (r & 7)) * 16);
        swz1 = (unsigned)(((q + 4) ^ (r & 7)) * 16);
#pragma unroll
        for (int MH = 0; MH < 2; ++MH)
#pragma unroll
            for (int mt = 0; mt < 4; ++mt)
                rowA[MH * 4 + mt] = asB + (unsigned)((arow0 + MH * 64 + mt * 16 + r) * 128);
#pragma unroll
        for (int NH = 0; NH < 2; ++NH)
#pragma unroll
            for (int nt = 0; nt < 2; ++nt)
                rowB[NH * 2 + nt] = bsB + (unsigned)((brow0 + NH * 32 + nt * 16 + r) * 128);
    }

    f32x4 acc[8][4] = {};

    if (!skip) {
        const int NT = kEnd >> 6;                    // >= 16 always (len>=1024)
        STAGE_T(0, 0);
        STAGE_T(1, 1);
        asm volatile("s_waitcnt vmcnt(8)" ::: "memory");   // tile 0 landed
        LDS_BAR;
        for (int t = 0; t < NT; ++t) {
            const int p = t & 1;
            const unsigned ps0 = (unsigned)(p << 15) + swz0;
            const unsigned ps1 = (unsigned)(p << 15) + swz1;
            bf16x8 a[2][4], b0[2][2], b1[2][2];
            // P1: read A(mh0)+B(nh0), compute quad (0,0)
            LD_A4(a, 0);
            LD_B2(b0, 0);
            LDS_BAR;
            WAIT_LGKM;
            __builtin_amdgcn_s_setprio(1);
            MFMA_QUAD(a, b0, 0, 0);
            __builtin_amdgcn_s_setprio(0);
            LDS_BAR;
            // P2: read B(nh1), compute quad (0,1)
            LD_B2(b1, 1);
            LDS_BAR;
            WAIT_LGKM;
            __builtin_amdgcn_s_setprio(1);
            MFMA_QUAD(a, b1, 0, 1);
            __builtin_amdgcn_s_setprio(0);
            LDS_BAR;
            // P3: read A(mh1), compute quad (1,1).  The WAIT_LGKM here plus the
            // closing barrier prove every wave's reads of buf[p] are COMPLETE
            // before any wave stages into buf[p] in P4.
            LD_A4(a, 1);
            LDS_BAR;
            WAIT_LGKM;
            __builtin_amdgcn_s_setprio(1);
            MFMA_QUAD(a, b1, 1, 1);
            __builtin_amdgcn_s_setprio(0);
            LDS_BAR;
            // P4: stage tile t+2 into buf[p], compute quad (1,0) from regs,
            // then counted vmcnt: oldest 8 outstanding = tile t+1.
            if (t + 2 < NT) STAGE_T(t + 2, p);
            __builtin_amdgcn_sched_barrier(0);
            __builtin_amdgcn_s_setprio(1);
            MFMA_QUAD(a, b0, 1, 0);
            __builtin_amdgcn_s_setprio(0);
            __builtin_amdgcn_sched_barrier(0);
            if (t + 2 < NT)      asm volatile("s_waitcnt vmcnt(8)" ::: "memory");
            else if (t + 1 < NT) asm volatile("s_waitcnt vmcnt(0)" ::: "memory");
            __builtin_amdgcn_s_barrier();
            __builtin_amdgcn_sched_barrier(0);
        }
    }

    // C/D layout per 16x16 fragment: col = lane&15, row = (lane>>4)*4 + i
    // acc[am][an]: row = arow0+(am>>2)*64+(am&3)*16+q*4+i,
    //              col = brow0+(an>>1)*32+(an&1)*16+r
    if (MODE == 5) {
        float* C = (float*)Cv + (size_t)bz * sC;
#pragma unroll
        for (int am = 0; am < 8; ++am) {
            size_t row = bm + arow0 + (am >> 2) * 64 + (am & 3) * 16 + q * 4;
#pragma unroll
            for (int an = 0; an < 4; ++an) {
                size_t col = bn + brow0 + (an >> 1) * 32 + (an & 1) * 16 + r;
#pragma unroll
                for (int i = 0; i < 4; ++i)
                    C[(row + i) * (size_t)ldc + col] = acc[am][an][i];
            }
        }
    } else if (MODE == 4) {
        u16* C = (u16*)Cv + (size_t)bz * sC;
#pragma unroll
        for (int am = 0; am < 8; ++am) {
            size_t row = bm + arow0 + (am >> 2) * 64 + (am & 3) * 16 + q * 4;
#pragma unroll
            for (int an = 0; an < 4; ++an) {
                size_t col = bn + brow0 + (an >> 1) * 32 + (an & 1) * 16 + r;
#pragma unroll
                for (int i = 0; i < 4; ++i)
                    C[(row + i) * (size_t)ldc + col] = f2h(acc[am][an][i]);
            }
        }
    } else {  // MODE 3: fused QKV epilogue, region uniform per block
        int region = blockIdx.y >> 2;                 // 0:Q 1:K 2:V
        if (region < 2) {
            u16* C = (u16*)Cv + (size_t)region * 16777216;  // Q or K [16384x1024]
            size_t cb = bn - (size_t)region * 1024;
#pragma unroll
            for (int am = 0; am < 8; ++am) {
                size_t row = bm + arow0 + (am >> 2) * 64 + (am & 3) * 16 + q * 4;
#pragma unroll
                for (int an = 0; an < 4; ++an) {
                    size_t col = cb + brow0 + (an >> 1) * 32 + (an & 1) * 16 + r;
#pragma unroll
                    for (int i = 0; i < 4; ++i)
                        C[(row + i) * 1024 + col] = f2bf(acc[am][an][i]);
                }
            }
        } else {
            // VT[b][d][t] = V[b*2048+t][d]; b = bm>>11 is BLOCK-UNIFORM
            // (256-row tiles never straddle the 2048-row batch boundary).
            // Each lane owns 4 consecutive t at fixed d -> one ushort4 store.
            u16* Cb = (u16*)Cv2 + (bm >> 11) * (size_t)(1024 * 2048)
                      + (bn - 2048) * 2048 + (bm & 2047);
#pragma unroll
            for (int an = 0; an < 4; ++an) {
                int cI = brow0 + (an >> 1) * 32 + (an & 1) * 16 + r;
#pragma unroll
                for (int am = 0; am < 8; ++am) {
                    int tI = arow0 + (am >> 2) * 64 + (am & 3) * 16 + q * 4;
                    ushort4 o;
                    o.x = f2bf(acc[am][an][0]);
                    o.y = f2bf(acc[am][an][1]);
                    o.z = f2bf(acc[am][an][2]);
                    o.w = f2bf(acc[am][an][3]);
                    *(ushort4*)(Cb + (size_t)cI * 2048 + tI) = o;
                }
            }
        }
    }
}

// ---- masked softmax, ONE ROW PER WAVE: fp16 row in, bf16 P in place (full row)
// Read and write both use us8 chunks: chunk c = j*64+lane covers cols c*8..c*8+7.
__global__ void softmax_rows_w(u16* __restrict__ E, const int* __restrict__ lengths) {
    int row  = blockIdx.x * 4 + (threadIdx.x >> 6);   // 16384 rows, 4 waves/block
    int lane = threadIdx.x & 63;
    int len  = lengths[row >> 11];
    u16* e = E + (size_t)row * 2048;

    float vals[32];
#pragma unroll
    for (int j = 0; j < 4; ++j) {
        us8 v = ((const us8*)e)[j * 64 + lane];
#pragma unroll
        for (int w = 0; w < 8; ++w) vals[j * 8 + w] = h2f(v[w]);
    }

    float m = -3.4e38f;
#pragma unroll
    for (int j = 0; j < 4; ++j) {
        int base = (j * 64 + lane) * 8;
#pragma unroll
        for (int w = 0; w < 8; ++w)
            if (base + w < len) m = fmaxf(m, vals[j * 8 + w]);
    }
#pragma unroll
    for (int off = 32; off; off >>= 1) m = fmaxf(m, __shfl_xor(m, off));

    const float C = 0.18033688011112042f;   // log2(e)/8  (scale 1/sqrt(64))
    float p[32]; float s = 0.f;
#pragma unroll
    for (int j = 0; j < 4; ++j) {
        int base = (j * 64 + lane) * 8;
#pragma unroll
        for (int w = 0; w < 8; ++w) {
            float v = (base + w < len) ? exp2f((vals[j * 8 + w] - m) * C) : 0.f;
            p[j * 8 + w] = v;
            s += v;
        }
    }
#pragma unroll
    for (int off = 32; off; off >>= 1) s += __shfl_xor(s, off);
    float rinv = 1.0f / s;

    // bf16 P over the fp16 row, identical chunk mapping as the read
#pragma unroll
    for (int j = 0; j < 4; ++j) {
        us8 o;
#pragma unroll
        for (int w = 0; w < 8; ++w) o[w] = f2bf(p[j * 8 + w] * rinv);
        ((us8*)e)[j * 64 + lane] = o;
    }
}

// ------------------------------------------------------------------ launch
extern "C" void kernel_launch(void* const* d_in, const int* in_sizes, int n_in,
                              void* d_out, int out_size, void* d_ws, size_t ws_size,
                              hipStream_t stream) {
    const float* x  = (const float*)d_in[0];
    const float* Wq = (const float*)d_in[1];
    const float* Wk = (const float*)d_in[2];
    const float* Wv = (const float*)d_in[3];
    float* out = (float*)d_out;
    char* ws = (char*)d_ws;

    const size_t SB  = 2097152;      // u16 elems per batch [2048x1024]
    const size_t SBe = 4194304;      // u16 elems per batch energy [2048x2048]

    // ws: lengths 256B | x16 32MB | WT 6MB | VT 32MB | E 64MB fp16 = 140,509,440 B
    if (ws_size < 140509440ULL) return;
    int* lengths = (int*)ws;
    u16* x16 = (u16*)(ws + 256);
    u16* WT  = (u16*)(ws + 33554688);
    u16* VT  = (u16*)(ws + 39846144);
    u16* E   = (u16*)(ws + 73400576);
    u16* Qb  = (u16*)d_out;                          // Q,K parked in d_out (64 MiB)
    u16* Kb  = Qb + 16777216;

    cast_x<<<dim3(16384), dim3(256), 0, stream>>>(x, x16);
    transpose_cast_w<<<dim3(32, 32, 3), dim3(32, 8), 0, stream>>>(Wq, Wk, Wv, WT);
    calc_lengths<<<dim3(8), dim3(256), 0, stream>>>(x, lengths);

    // fused QKV: x16[16384x1024] @ WT[3072x1024]^T -> Q,K (d_out) + VT (ws)
    gemm_bt<3><<<dim3(64, 12, 1), 512, 0, stream>>>(x16, 1024, 0, WT, 1024, 0,
                                                    Qb, VT, 1024, 0, 1024, lengths);

    // energy[b] = Q_b K_b^T -> fp16 E; bn>=len skipped, bm>=len zero-filled
    gemm_bt<4><<<dim3(8, 8, 8), 512, 0, stream>>>(Qb, 1024, SB, Kb, 1024, SB,
                                                  E, nullptr, 2048, SBe, 1024, lengths);

    // masked softmax -> bf16 P in place (one row per wave)
    softmax_rows_w<<<dim3(4096), dim3(256), 0, stream>>>(E, lengths);

    // out[b] = P_b V_b = P_b (VT_b)^T; K clamped to round64(len[b])
    gemm_bt<5><<<dim3(8, 4, 8), 512, 0, stream>>>(E, 2048, SBe, VT, 2048, SB,
                                                  out, nullptr, 1024, SB, 2048, lengths);
}

// Round 4
// 389.591 us; speedup vs baseline: 1.0668x; 1.0022x over previous
//
#include <hip/hip_runtime.h>
#include <hip/hip_bf16.h>

// B=8, T=2048, E=1024, D=DK*H=1024 (heads fused in reference math)
//   QKV = x @ [Wq|Wk|Wv]  fused GEMM  [16384 x 3072] bf16 (V stored transposed);
//         m-blocks entirely beyond len[b] skip compute and store zeros.
//   energy[b] = Q_b K_b^T  fp16; n-blocks bn>=len skipped; m-blocks bm>=len
//         store exact zeros (Q rows are zero) without compute.
//   lengths[b] = #nonzero rows of x[b]
//   P = softmax(mask(energy)/8) bf16 in place over fp16 rows (one row per wave)
//   out[b] = P_b V_b  fp32; K-loop clamped to round64(len[b]).
//
// R12 (= R11 resubmit): R11's bench died at the container level (no pytest
// fail, no counters) -> most likely infra. Deadlock audit: barriers are
// block-uniform (skip uniform, MODE4 return precedes all barriers), waitcnts
// cannot deadlock, counted lgkm valid under the 15-entry cap (issue throttles,
// DS completes in-order), a[] time-share WAR is latency-safe (LDS writeback
// >=100cyc after in-order issue, past the last MFMA operand-capture window).
// Schedule (unchanged): counted-lgkm intra-tile pipeline, TWO barriers/K-tile:
//   issue B0,A0,B1 (16 ds_reads) -> lgkm(4) -> MFMA(0,0)
//   lgkm(0) -> MFMA(0,1)
//   issue A1 time-sharing a[] -> lgkm(0) -> MFMA(1,1)+(1,0)
//   BAR [WAR] -> stage(t+2) -> vmcnt(8) [tile t+1 landed] -> BAR [RAW]
// R2 cost model: 6300 cyc/tile = serial LDS phases + serial MFMA + 8 barriers.
// This overlaps read-drain with MFMA backlog: predicted ~4000 cyc/tile.
// ws = 140,509,440 B: lengths 256B | x16 32MB | WT 6MB | VT 32MB | E 64MB fp16.

typedef unsigned short u16;
typedef __bf16 bf16x8 __attribute__((ext_vector_type(8)));
typedef float f32x4 __attribute__((ext_vector_type(4)));
typedef unsigned short us8 __attribute__((ext_vector_type(8)));

__device__ __forceinline__ u16 f2bf(float f) {
    union { float f; unsigned u; } x; x.f = f;
    unsigned r = x.u + 0x7FFFu + ((x.u >> 16) & 1u);   // RNE
    return (u16)(r >> 16);
}
__device__ __forceinline__ u16 f2h(float f) {
    union { _Float16 h; u16 u; } c; c.h = (_Float16)f;
    return c.u;
}
__device__ __forceinline__ float h2f(u16 b) {
    union { u16 u; _Float16 h; } c; c.u = b;
    return (float)c.h;
}

__device__ __forceinline__ void gload_lds16(const void* g, void* l) {
    __builtin_amdgcn_global_load_lds(
        (const __attribute__((address_space(1))) unsigned*)g,
        (__attribute__((address_space(3))) unsigned*)l, 16, 0, 0);
}

// 32-bit LDS byte offset of a __shared__ object (addrspace(3) ptrs are 32-bit)
__device__ __forceinline__ unsigned lds_off(const void* p) {
    return (unsigned)(size_t)(const __attribute__((address_space(3))) char*)p;
}
// opaque LDS read: no alias edge to global_load_lds -> no compiler vmcnt drain
__device__ __forceinline__ bf16x8 ds_read16(unsigned a) {
    bf16x8 r;
    asm volatile("ds_read_b128 %0, %1" : "=v"(r) : "v"(a));
    return r;
}

// ---------------------------------------------------------------- cast x -> bf16
__global__ void cast_x(const float* __restrict__ x, u16* __restrict__ o) {
    int i = blockIdx.x * 256 + threadIdx.x;          // float4 index
    float4 v = ((const float4*)x)[i];
    ushort4 u;
    u.x = f2bf(v.x); u.y = f2bf(v.y); u.z = f2bf(v.z); u.w = f2bf(v.w);
    ((ushort4*)o)[i] = u;
}

// ------------------------------------------------- W[e][n] -> WT[n][e] bf16, x3
__global__ void transpose_cast_w(const float* __restrict__ Wq,
                                 const float* __restrict__ Wk,
                                 const float* __restrict__ Wv,
                                 u16* __restrict__ WT) {
    __shared__ float tile[32][33];
    const float* W = (blockIdx.z == 0) ? Wq : (blockIdx.z == 1) ? Wk : Wv;
    u16* T = WT + (size_t)blockIdx.z * 1048576;
    int n0 = blockIdx.x * 32, e0 = blockIdx.y * 32;
    int tx = threadIdx.x, ty = threadIdx.y;
#pragma unroll
    for (int j = 0; j < 4; ++j) {
        int e = ty + j * 8;
        tile[e][tx] = W[(size_t)(e0 + e) * 1024 + (n0 + tx)];
    }
    __syncthreads();
#pragma unroll
    for (int j = 0; j < 4; ++j) {
        int n = ty + j * 8;
        T[(size_t)(n0 + n) * 1024 + (e0 + tx)] = f2bf(tile[tx][n]);
    }
}

// ----------------------------------------------------- lengths[b] from x rows
__global__ void calc_lengths(const float* __restrict__ x, int* __restrict__ len) {
    int b = blockIdx.x, tid = threadIdx.x;
    int cnt = 0;
    for (int t = tid; t < 2048; t += 256) {
        float4 v = *(const float4*)(x + ((size_t)b * 2048 + t) * 1024);
        cnt += (v.x != 0.f || v.y != 0.f || v.z != 0.f || v.w != 0.f) ? 1 : 0;
    }
#pragma unroll
    for (int off = 32; off; off >>= 1) cnt += __shfl_xor(cnt, off);
    __shared__ int red[4];
    int wid = tid >> 6, lane = tid & 63;
    if (!lane) red[wid] = cnt;
    __syncthreads();
    if (tid == 0) len[b] = red[0] + red[1] + red[2] + red[3];
}

// ------------------------------------------------------------- bf16 NT GEMM
// 256x256 tile, BK=64, pipelined (2 barriers/K-tile). C[m,n]=sum_k A[m,k]B[n,k].
// MODE 3: fused-QKV routing (y 0-3 Q, 4-7 K, 8-11 V transposed into Cv2)
// MODE 4: energy fp16; n-blocks bn>=len return; m-blocks bm>=len store zeros
// MODE 5: PV fp32; K clamped to round64(len)

#define SBAR0 __builtin_amdgcn_sched_barrier(0)

#define STAGE_T(KT, BUF) do { \
  _Pragma("unroll") for (int j_ = 0; j_ < 4; ++j_) \
      gload_lds16(A + offA[j_] + (size_t)(KT) * 64, &As[BUF][ldsC[j_]]); \
  _Pragma("unroll") for (int j_ = 0; j_ < 4; ++j_) \
      gload_lds16(B + offB[j_] + (size_t)(KT) * 64, &Bs[BUF][ldsC[j_]]); \
} while (0)

// fragment reads: precomputed row-base addresses + per-tile parity/swizzle add
#define LD_A4(AF, MH) do { \
  _Pragma("unroll") for (int mt_ = 0; mt_ < 4; ++mt_) { \
    AF[0][mt_] = ds_read16(rowA[(MH) * 4 + mt_] + ps0); \
    AF[1][mt_] = ds_read16(rowA[(MH) * 4 + mt_] + ps1); \
  } \
} while (0)

#define LD_B2(BF, NH) do { \
  _Pragma("unroll") for (int nt_ = 0; nt_ < 2; ++nt_) { \
    BF[0][nt_] = ds_read16(rowB[(NH) * 2 + nt_] + ps0); \
    BF[1][nt_] = ds_read16(rowB[(NH) * 2 + nt_] + ps1); \
  } \
} while (0)

#define MFMA_QUAD(AF, BF, MH, NH) do { \
  _Pragma("unroll") for (int s_ = 0; s_ < 2; ++s_) \
  _Pragma("unroll") for (int mt_ = 0; mt_ < 4; ++mt_) \
  _Pragma("unroll") for (int nt_ = 0; nt_ < 2; ++nt_) \
    acc[(MH) * 4 + mt_][(NH) * 2 + nt_] = __builtin_amdgcn_mfma_f32_16x16x32_bf16( \
        AF[s_][mt_], BF[s_][nt_], acc[(MH) * 4 + mt_][(NH) * 2 + nt_], 0, 0, 0); \
} while (0)

template <int MODE>
__global__ __launch_bounds__(512, 2)   // 8 waves, <=256 unified regs
void gemm_bt(const u16* __restrict__ A, int lda, size_t sA,
             const u16* __restrict__ B, int ldb, size_t sB,
             void* __restrict__ Cv, void* __restrict__ Cv2,
             int ldc, size_t sC, int Kdim, const int* __restrict__ lenp) {
    __shared__ u16 As[2][256 * 64];    // 64 KiB (32 KiB per parity buffer)
    __shared__ u16 Bs[2][256 * 64];    // 64 KiB
    const int tid = threadIdx.x;
    const int bz  = blockIdx.z;
    A += (size_t)bz * sA;
    B += (size_t)bz * sB;
    const size_t bm = (size_t)blockIdx.x * 256, bn = (size_t)blockIdx.y * 256;

    bool skip = false;
    int kEnd = Kdim;
    if (MODE == 3) {
        int lenz = lenp[bm >> 11];
        skip = ((int)(bm & 2047) >= lenz);           // whole tile rows are zero
    } else if (MODE == 4) {
        int lenz = lenp[bz];
        if ((int)bn >= lenz) return;                 // cols fully masked: unread
        skip = ((int)bm >= lenz);                    // Q rows zero -> energy 0
    } else if (MODE == 5) {
        int lenz = lenp[bz];
        int r64 = (lenz + 63) & ~63;
        kEnd = r64 < Kdim ? r64 : Kdim;              // P cols >= len are zeros
    }

    const int wid = tid >> 6, lane = tid & 63;
    const int wm = wid >> 2, wn = wid & 3;           // 2M x 4N wave grid
    const int q = lane >> 4, r = lane & 15;
    const int arow0 = wm * 128, brow0 = wn * 64;

    // staging: each matrix tile = 2048 x 16B chunks; thread owns c = j*512+tid.
    // chunk c -> linear LDS byte c*16 (wave-contiguous: base + lane*16);
    // global source column pre-swizzled so LDS[linear] == swizzled layout.
    size_t offA[4], offB[4]; int ldsC[4];
#pragma unroll
    for (int j = 0; j < 4; ++j) {
        int c = j * 512 + tid;
        int row = c >> 3;
        int c16 = (c & 7) ^ (row & 7);               // inverse(=same) swizzle
        offA[j] = (size_t)(bm + row) * lda + c16 * 8;
        offB[j] = (size_t)(bn + row) * ldb + c16 * 8;
        ldsC[j] = c * 8;
    }

    // precomputed LDS read addresses (buf0): row base + swizzled 16B chunk
    unsigned rowA[8], rowB[4], swz0, swz1;
    {
        unsigned asB = lds_off(&As[0][0]), bsB = lds_off(&Bs[0][0]);
        swz0 = (unsigned)((q ^ (r & 7)) * 16);
        swz1 = (unsigned)(((q + 4) ^ (r & 7)) * 16);
#pragma unroll
        for (int MH = 0; MH < 2; ++MH)
#pragma unroll
            for (int mt = 0; mt < 4; ++mt)
                rowA[MH * 4 + mt] = asB + (unsigned)((arow0 + MH * 64 + mt * 16 + r) * 128);
#pragma unroll
        for (int NH = 0; NH < 2; ++NH)
#pragma unroll
            for (int nt = 0; nt < 2; ++nt)
                rowB[NH * 2 + nt] = bsB + (unsigned)((brow0 + NH * 32 + nt * 16 + r) * 128);
    }

    f32x4 acc[8][4] = {};

    if (!skip) {
        const int NT = kEnd >> 6;                    // >= 16 always (len>=1024)
        STAGE_T(0, 0);
        STAGE_T(1, 1);
        asm volatile("s_waitcnt vmcnt(8)" ::: "memory");   // tile 0 landed
        SBAR0; __builtin_amdgcn_s_barrier(); SBAR0;
        for (int t = 0; t < NT; ++t) {
            const int p = t & 1;
            const unsigned ps0 = (unsigned)(p << 15) + swz0;
            const unsigned ps1 = (unsigned)(p << 15) + swz1;
            bf16x8 a[2][4], b0[2][2], b1[2][2];
            // issue 16 ds_reads: B0 first so lgkm(4) covers B0+A0
            LD_B2(b0, 0);
            LD_A4(a, 0);
            LD_B2(b1, 1);
            asm volatile("s_waitcnt lgkmcnt(4)" ::: "memory");  // B0,A0 done
            SBAR0;
            __builtin_amdgcn_s_setprio(1);
            MFMA_QUAD(a, b0, 0, 0);
            __builtin_amdgcn_s_setprio(0);
            SBAR0;
            asm volatile("s_waitcnt lgkmcnt(0)" ::: "memory");  // B1 done
            SBAR0;
            __builtin_amdgcn_s_setprio(1);
            MFMA_QUAD(a, b1, 0, 1);
            __builtin_amdgcn_s_setprio(0);
            SBAR0;   // pin: A1 reads AFTER (0,1) issue -> regalloc reuses a[]
            LD_A4(a, 1);                      // A1 time-shares a[] (A0 dead)
            asm volatile("s_waitcnt lgkmcnt(0)" ::: "memory");  // A1 done
            SBAR0;
            __builtin_amdgcn_s_setprio(1);
            MFMA_QUAD(a, b1, 1, 1);
            MFMA_QUAD(a, b0, 1, 0);
            __builtin_amdgcn_s_setprio(0);
            SBAR0;
            // every wave has drained its reads of buf[p] (lgkm(0) above):
            __builtin_amdgcn_s_barrier();     // WAR: reads done before stage
            SBAR0;
            if (t + 2 < NT) STAGE_T(t + 2, p);
            SBAR0;
            if (t + 2 < NT)      asm volatile("s_waitcnt vmcnt(8)" ::: "memory");
            else if (t + 1 < NT) asm volatile("s_waitcnt vmcnt(0)" ::: "memory");
            __builtin_amdgcn_s_barrier();     // RAW: tile t+1 landed for all
            SBAR0;
        }
    }

    // C/D layout per 16x16 fragment: col = lane&15, row = (lane>>4)*4 + i
    // acc[am][an]: row = arow0+(am>>2)*64+(am&3)*16+q*4+i,
    //              col = brow0+(an>>1)*32+(an&1)*16+r
    if (MODE == 5) {
        float* C = (float*)Cv + (size_t)bz * sC;
#pragma unroll
        for (int am = 0; am < 8; ++am) {
            size_t row = bm + arow0 + (am >> 2) * 64 + (am & 3) * 16 + q * 4;
#pragma unroll
            for (int an = 0; an < 4; ++an) {
                size_t col = bn + brow0 + (an >> 1) * 32 + (an & 1) * 16 + r;
#pragma unroll
                for (int i = 0; i < 4; ++i)
                    C[(row + i) * (size_t)ldc + col] = acc[am][an][i];
            }
        }
    } else if (MODE == 4) {
        u16* C = (u16*)Cv + (size_t)bz * sC;
#pragma unroll
        for (int am = 0; am < 8; ++am) {
            size_t row = bm + arow0 + (am >> 2) * 64 + (am & 3) * 16 + q * 4;
#pragma unroll
            for (int an = 0; an < 4; ++an) {
                size_t col = bn + brow0 + (an >> 1) * 32 + (an & 1) * 16 + r;
#pragma unroll
                for (int i = 0; i < 4; ++i)
                    C[(row + i) * (size_t)ldc + col] = f2h(acc[am][an][i]);
            }
        }
    } else {  // MODE 3: fused QKV epilogue, region uniform per block
        int region = blockIdx.y >> 2;                 // 0:Q 1:K 2:V
        if (region < 2) {
            u16* C = (u16*)Cv + (size_t)region * 16777216;  // Q or K [16384x1024]
            size_t cb = bn - (size_t)region * 1024;
#pragma unroll
            for (int am = 0; am < 8; ++am) {
                size_t row = bm + arow0 + (am >> 2) * 64 + (am & 3) * 16 + q * 4;
#pragma unroll
                for (int an = 0; an < 4; ++an) {
                    size_t col = cb + brow0 + (an >> 1) * 32 + (an & 1) * 16 + r;
#pragma unroll
                    for (int i = 0; i < 4; ++i)
                        C[(row + i) * 1024 + col] = f2bf(acc[am][an][i]);
                }
            }
        } else {
            // VT[b][d][t] = V[b*2048+t][d]; b = bm>>11 is BLOCK-UNIFORM
            // (256-row tiles never straddle the 2048-row batch boundary).
            // Each lane owns 4 consecutive t at fixed d -> one ushort4 store.
            u16* Cb = (u16*)Cv2 + (bm >> 11) * (size_t)(1024 * 2048)
                      + (bn - 2048) * 2048 + (bm & 2047);
#pragma unroll
            for (int an = 0; an < 4; ++an) {
                int cI = brow0 + (an >> 1) * 32 + (an & 1) * 16 + r;
#pragma unroll
                for (int am = 0; am < 8; ++am) {
                    int tI = arow0 + (am >> 2) * 64 + (am & 3) * 16 + q * 4;
                    ushort4 o;
                    o.x = f2bf(acc[am][an][0]);
                    o.y = f2bf(acc[am][an][1]);
                    o.z = f2bf(acc[am][an][2]);
                    o.w = f2bf(acc[am][an][3]);
                    *(ushort4*)(Cb + (size_t)cI * 2048 + tI) = o;
                }
            }
        }
    }
}

// ---- masked softmax, ONE ROW PER WAVE: fp16 row in, bf16 P in place (full row)
// Read and write both use us8 chunks: chunk c = j*64+lane covers cols c*8..c*8+7.
__global__ void softmax_rows_w(u16* __restrict__ E, const int* __restrict__ lengths) {
    int row  = blockIdx.x * 4 + (threadIdx.x >> 6);   // 16384 rows, 4 waves/block
    int lane = threadIdx.x & 63;
    int len  = lengths[row >> 11];
    u16* e = E + (size_t)row * 2048;

    float vals[32];
#pragma unroll
    for (int j = 0; j < 4; ++j) {
        us8 v = ((const us8*)e)[j * 64 + lane];
#pragma unroll
        for (int w = 0; w < 8; ++w) vals[j * 8 + w] = h2f(v[w]);
    }

    float m = -3.4e38f;
#pragma unroll
    for (int j = 0; j < 4; ++j) {
        int base = (j * 64 + lane) * 8;
#pragma unroll
        for (int w = 0; w < 8; ++w)
            if (base + w < len) m = fmaxf(m, vals[j * 8 + w]);
    }
#pragma unroll
    for (int off = 32; off; off >>= 1) m = fmaxf(m, __shfl_xor(m, off));

    const float C = 0.18033688011112042f;   // log2(e)/8  (scale 1/sqrt(64))
    float p[32]; float s = 0.f;
#pragma unroll
    for (int j = 0; j < 4; ++j) {
        int base = (j * 64 + lane) * 8;
#pragma unroll
        for (int w = 0; w < 8; ++w) {
            float v = (base + w < len) ? exp2f((vals[j * 8 + w] - m) * C) : 0.f;
            p[j * 8 + w] = v;
            s += v;
        }
    }
#pragma unroll
    for (int off = 32; off; off >>= 1) s += __shfl_xor(s, off);
    float rinv = 1.0f / s;

    // bf16 P over the fp16 row, identical chunk mapping as the read
#pragma unroll
    for (int j = 0; j < 4; ++j) {
        us8 o;
#pragma unroll
        for (int w = 0; w < 8; ++w) o[w] = f2bf(p[j * 8 + w] * rinv);
        ((us8*)e)[j * 64 + lane] = o;
    }
}

// ------------------------------------------------------------------ launch
extern "C" void kernel_launch(void* const* d_in, const int* in_sizes, int n_in,
                              void* d_out, int out_size, void* d_ws, size_t ws_size,
                              hipStream_t stream) {
    const float* x  = (const float*)d_in[0];
    const float* Wq = (const float*)d_in[1];
    const float* Wk = (const float*)d_in[2];
    const float* Wv = (const float*)d_in[3];
    float* out = (float*)d_out;
    char* ws = (char*)d_ws;

    const size_t SB  = 2097152;      // u16 elems per batch [2048x1024]
    const size_t SBe = 4194304;      // u16 elems per batch energy [2048x2048]

    // ws: lengths 256B | x16 32MB | WT 6MB | VT 32MB | E 64MB fp16 = 140,509,440 B
    if (ws_size < 140509440ULL) return;
    int* lengths = (int*)ws;
    u16* x16 = (u16*)(ws + 256);
    u16* WT  = (u16*)(ws + 33554688);
    u16* VT  = (u16*)(ws + 39846144);
    u16* E   = (u16*)(ws + 73400576);
    u16* Qb  = (u16*)d_out;                          // Q,K parked in d_out (64 MiB)
    u16* Kb  = Qb + 16777216;

    cast_x<<<dim3(16384), dim3(256), 0, stream>>>(x, x16);
    transpose_cast_w<<<dim3(32, 32, 3), dim3(32, 8), 0, stream>>>(Wq, Wk, Wv, WT);
    calc_lengths<<<dim3(8), dim3(256), 0, stream>>>(x, lengths);

    // fused QKV: x16[16384x1024] @ WT[3072x1024]^T -> Q,K (d_out) + VT (ws)
    gemm_bt<3><<<dim3(64, 12, 1), 512, 0, stream>>>(x16, 1024, 0, WT, 1024, 0,
                                                    Qb, VT, 1024, 0, 1024, lengths);

    // energy[b] = Q_b K_b^T -> fp16 E; bn>=len skipped, bm>=len zero-filled
    gemm_bt<4><<<dim3(8, 8, 8), 512, 0, stream>>>(Qb, 1024, SB, Kb, 1024, SB,
                                                  E, nullptr, 2048, SBe, 1024, lengths);

    // masked softmax -> bf16 P in place (one row per wave)
    softmax_rows_w<<<dim3(4096), dim3(256), 0, stream>>>(E, lengths);

    // out[b] = P_b V_b = P_b (VT_b)^T; K clamped to round64(len[b])
    gemm_bt<5><<<dim3(8, 4, 8), 512, 0, stream>>>(E, 2048, SBe, VT, 2048, SB,
                                                  out, nullptr, 1024, SB, 2048, lengths);
}

// Round 5
// 382.481 us; speedup vs baseline: 1.0866x; 1.0186x over previous
//
#include <hip/hip_runtime.h>
#include <hip/hip_bf16.h>

// B=8, T=2048, E=1024, D=DK*H=1024 (heads fused in reference math)
//   QKV = x @ [Wq|Wk|Wv]  fused GEMM  [16384 x 3072] bf16 (V stored transposed);
//         m-blocks entirely beyond len[b] skip compute and store zeros.
//   energy[b] = Q_b K_b^T  fp16; n-blocks bn>=len skipped; m-blocks bm>=len
//         store exact zeros (Q rows are zero) without compute.
//   lengths[b] = #nonzero rows of x[b]
//   P = softmax(mask(energy)/8) bf16 in place over fp16 rows (one row per wave)
//   out[b] = P_b V_b  fp32; K-loop clamped to round64(len[b]).
//
// R13: R1 had the 8-phase structure but compiler-drained C++ LDS reads;
// R2/R4 had asm reads but a COARSE schedule (8-gload burst + vmcnt(8) 2-deep
// = m196's measured -7..-27% variant). Model: 45.7% (m198) x 0.75 (coarse)
// x 0.85 (16-tile rounds) = 29% = measured. This round combines BOTH halves
// faithfully (m201 template):
//   per K-tile, 4 phases: {asm ds_reads for this quad | stage ONE half-tile
//   (2 gload_lds) | lgkm(8) if 12 reads} BAR lgkm(0) prio1 16xMFMA prio0 BAR
//   vmcnt(2) ONLY at phase 4 (counted, never 0 in-loop).
// Staging spread (WAR-safe): tile t+1 halves h1..h3 stage in t.ph1..ph3
// (target buf[p^1], not read by tile t); tile t+2 h0 stages at t.ph4 (after
// ph3's lgkm(0)+barrier drains all reads of buf[p]). vmcnt(2) at ph4-close
// leaves only the newest half outstanding => tile t+1 fully landed.
// ws = 140,509,440 B: lengths 256B | x16 32MB | WT 6MB | VT 32MB | E 64MB fp16.

typedef unsigned short u16;
typedef __bf16 bf16x8 __attribute__((ext_vector_type(8)));
typedef float f32x4 __attribute__((ext_vector_type(4)));
typedef unsigned short us8 __attribute__((ext_vector_type(8)));

__device__ __forceinline__ u16 f2bf(float f) {
    union { float f; unsigned u; } x; x.f = f;
    unsigned r = x.u + 0x7FFFu + ((x.u >> 16) & 1u);   // RNE
    return (u16)(r >> 16);
}
__device__ __forceinline__ u16 f2h(float f) {
    union { _Float16 h; u16 u; } c; c.h = (_Float16)f;
    return c.u;
}
__device__ __forceinline__ float h2f(u16 b) {
    union { u16 u; _Float16 h; } c; c.u = b;
    return (float)c.h;
}

__device__ __forceinline__ void gload_lds16(const void* g, void* l) {
    __builtin_amdgcn_global_load_lds(
        (const __attribute__((address_space(1))) unsigned*)g,
        (__attribute__((address_space(3))) unsigned*)l, 16, 0, 0);
}

// 32-bit LDS byte offset of a __shared__ object (addrspace(3) ptrs are 32-bit)
__device__ __forceinline__ unsigned lds_off(const void* p) {
    return (unsigned)(size_t)(const __attribute__((address_space(3))) char*)p;
}
// opaque LDS read: no alias edge to global_load_lds -> no compiler vmcnt drain
__device__ __forceinline__ bf16x8 ds_read16(unsigned a) {
    bf16x8 r;
    asm volatile("ds_read_b128 %0, %1" : "=v"(r) : "v"(a));
    return r;
}

// ---------------------------------------------------------------- cast x -> bf16
__global__ void cast_x(const float* __restrict__ x, u16* __restrict__ o) {
    int i = blockIdx.x * 256 + threadIdx.x;          // float4 index
    float4 v = ((const float4*)x)[i];
    ushort4 u;
    u.x = f2bf(v.x); u.y = f2bf(v.y); u.z = f2bf(v.z); u.w = f2bf(v.w);
    ((ushort4*)o)[i] = u;
}

// ------------------------------------------------- W[e][n] -> WT[n][e] bf16, x3
__global__ void transpose_cast_w(const float* __restrict__ Wq,
                                 const float* __restrict__ Wk,
                                 const float* __restrict__ Wv,
                                 u16* __restrict__ WT) {
    __shared__ float tile[32][33];
    const float* W = (blockIdx.z == 0) ? Wq : (blockIdx.z == 1) ? Wk : Wv;
    u16* T = WT + (size_t)blockIdx.z * 1048576;
    int n0 = blockIdx.x * 32, e0 = blockIdx.y * 32;
    int tx = threadIdx.x, ty = threadIdx.y;
#pragma unroll
    for (int j = 0; j < 4; ++j) {
        int e = ty + j * 8;
        tile[e][tx] = W[(size_t)(e0 + e) * 1024 + (n0 + tx)];
    }
    __syncthreads();
#pragma unroll
    for (int j = 0; j < 4; ++j) {
        int n = ty + j * 8;
        T[(size_t)(n0 + n) * 1024 + (e0 + tx)] = f2bf(tile[tx][n]);
    }
}

// ----------------------------------------------------- lengths[b] from x rows
__global__ void calc_lengths(const float* __restrict__ x, int* __restrict__ len) {
    int b = blockIdx.x, tid = threadIdx.x;
    int cnt = 0;
    for (int t = tid; t < 2048; t += 256) {
        float4 v = *(const float4*)(x + ((size_t)b * 2048 + t) * 1024);
        cnt += (v.x != 0.f || v.y != 0.f || v.z != 0.f || v.w != 0.f) ? 1 : 0;
    }
#pragma unroll
    for (int off = 32; off; off >>= 1) cnt += __shfl_xor(cnt, off);
    __shared__ int red[4];
    int wid = tid >> 6, lane = tid & 63;
    if (!lane) red[wid] = cnt;
    __syncthreads();
    if (tid == 0) len[b] = red[0] + red[1] + red[2] + red[3];
}

// ------------------------------------------------------------- bf16 NT GEMM
// 256x256 tile, BK=64, 8-phase fine-interleaved pipeline (2 barriers/phase).
// MODE 3: fused-QKV routing (y 0-3 Q, 4-7 K, 8-11 V transposed into Cv2)
// MODE 4: energy fp16; n-blocks bn>=len return; m-blocks bm>=len store zeros
// MODE 5: PV fp32; K clamped to round64(len)

#define SBAR0 __builtin_amdgcn_sched_barrier(0)
#define BARRIER do { SBAR0; __builtin_amdgcn_s_barrier(); SBAR0; } while (0)

// stage ONE half-tile (2 x global_load_lds, 16 KB): H=0,1 -> A halves; 2,3 -> B
#define STAGE_HALF(KT, H) do { \
  if ((H) < 2) { \
    gload_lds16(A + offA[(H)*2]     + (size_t)(KT) * 64, &As[(KT)&1][ldsC[(H)*2]]); \
    gload_lds16(A + offA[(H)*2 + 1] + (size_t)(KT) * 64, &As[(KT)&1][ldsC[(H)*2 + 1]]); \
  } else { \
    gload_lds16(B + offB[((H)-2)*2]     + (size_t)(KT) * 64, &Bs[(KT)&1][ldsC[((H)-2)*2]]); \
    gload_lds16(B + offB[((H)-2)*2 + 1] + (size_t)(KT) * 64, &Bs[(KT)&1][ldsC[((H)-2)*2 + 1]]); \
  } \
} while (0)

// fragment reads: precomputed row-base addresses + per-tile parity/swizzle add
#define LD_A4(AF, MH) do { \
  _Pragma("unroll") for (int mt_ = 0; mt_ < 4; ++mt_) { \
    AF[0][mt_] = ds_read16(rowA[(MH) * 4 + mt_] + ps0); \
    AF[1][mt_] = ds_read16(rowA[(MH) * 4 + mt_] + ps1); \
  } \
} while (0)

#define LD_B2(BF, NH) do { \
  _Pragma("unroll") for (int nt_ = 0; nt_ < 2; ++nt_) { \
    BF[0][nt_] = ds_read16(rowB[(NH) * 2 + nt_] + ps0); \
    BF[1][nt_] = ds_read16(rowB[(NH) * 2 + nt_] + ps1); \
  } \
} while (0)

#define MFMA_QUAD(AF, BF, MH, NH) do { \
  _Pragma("unroll") for (int s_ = 0; s_ < 2; ++s_) \
  _Pragma("unroll") for (int mt_ = 0; mt_ < 4; ++mt_) \
  _Pragma("unroll") for (int nt_ = 0; nt_ < 2; ++nt_) \
    acc[(MH) * 4 + mt_][(NH) * 2 + nt_] = __builtin_amdgcn_mfma_f32_16x16x32_bf16( \
        AF[s_][mt_], BF[s_][nt_], acc[(MH) * 4 + mt_][(NH) * 2 + nt_], 0, 0, 0); \
} while (0)

#define WAIT_LGKM0 do { asm volatile("s_waitcnt lgkmcnt(0)" ::: "memory"); SBAR0; } while (0)

template <int MODE>
__global__ __launch_bounds__(512, 2)   // 8 waves, <=256 unified regs
void gemm_bt(const u16* __restrict__ A, int lda, size_t sA,
             const u16* __restrict__ B, int ldb, size_t sB,
             void* __restrict__ Cv, void* __restrict__ Cv2,
             int ldc, size_t sC, int Kdim, const int* __restrict__ lenp) {
    __shared__ u16 As[2][256 * 64];    // 64 KiB (32 KiB per parity buffer)
    __shared__ u16 Bs[2][256 * 64];    // 64 KiB
    const int tid = threadIdx.x;
    const int bz  = blockIdx.z;
    A += (size_t)bz * sA;
    B += (size_t)bz * sB;
    const size_t bm = (size_t)blockIdx.x * 256, bn = (size_t)blockIdx.y * 256;

    bool skip = false;
    int kEnd = Kdim;
    if (MODE == 3) {
        int lenz = lenp[bm >> 11];
        skip = ((int)(bm & 2047) >= lenz);           // whole tile rows are zero
    } else if (MODE == 4) {
        int lenz = lenp[bz];
        if ((int)bn >= lenz) return;                 // cols fully masked: unread
        skip = ((int)bm >= lenz);                    // Q rows zero -> energy 0
    } else if (MODE == 5) {
        int lenz = lenp[bz];
        int r64 = (lenz + 63) & ~63;
        kEnd = r64 < Kdim ? r64 : Kdim;              // P cols >= len are zeros
    }

    const int wid = tid >> 6, lane = tid & 63;
    const int wm = wid >> 2, wn = wid & 3;           // 2M x 4N wave grid
    const int q = lane >> 4, r = lane & 15;
    const int arow0 = wm * 128, brow0 = wn * 64;

    // staging: each matrix tile = 2048 x 16B chunks; thread owns c = j*512+tid.
    // chunk c -> linear LDS byte c*16 (wave-contiguous: base + lane*16);
    // global source column pre-swizzled so LDS[linear] == swizzled layout.
    size_t offA[4], offB[4]; int ldsC[4];
#pragma unroll
    for (int j = 0; j < 4; ++j) {
        int c = j * 512 + tid;
        int row = c >> 3;
        int c16 = (c & 7) ^ (row & 7);               // inverse(=same) swizzle
        offA[j] = (size_t)(bm + row) * lda + c16 * 8;
        offB[j] = (size_t)(bn + row) * ldb + c16 * 8;
        ldsC[j] = c * 8;
    }

    // precomputed LDS read addresses (buf0): row base + swizzled 16B chunk
    unsigned rowA[8], rowB[4], swz0, swz1;
    {
        unsigned asB = lds_off(&As[0][0]), bsB = lds_off(&Bs[0][0]);
        swz0 = (unsigned)((q ^ (r & 7)) * 16);
        swz1 = (unsigned)(((q + 4) ^ (r & 7)) * 16);
#pragma unroll
        for (int MH = 0; MH < 2; ++MH)
#pragma unroll
            for (int mt = 0; mt < 4; ++mt)
                rowA[MH * 4 + mt] = asB + (unsigned)((arow0 + MH * 64 + mt * 16 + r) * 128);
#pragma unroll
        for (int NH = 0; NH < 2; ++NH)
#pragma unroll
            for (int nt = 0; nt < 2; ++nt)
                rowB[NH * 2 + nt] = bsB + (unsigned)((brow0 + NH * 32 + nt * 16 + r) * 128);
    }

    f32x4 acc[8][4] = {};

    if (!skip) {
        const int NT = kEnd >> 6;                    // >= 16 always (len>=1024)
        // prologue: tile0 fully + tile1 h0; vmcnt(2) -> tile0 landed
        STAGE_HALF(0, 0); STAGE_HALF(0, 1); STAGE_HALF(0, 2); STAGE_HALF(0, 3);
        STAGE_HALF(1, 0);
        asm volatile("s_waitcnt vmcnt(2)" ::: "memory");
        BARRIER;
        for (int t = 0; t < NT; ++t) {
            const int p = t & 1;
            const unsigned ps0 = (unsigned)(p << 15) + swz0;
            const unsigned ps1 = (unsigned)(p << 15) + swz1;
            bf16x8 a[2][4], b0[2][2], b1[2][2];
            // ---- phase 1: quad (0,0); stage tile t+1 half1 (buf p^1, unread
            //      by tile t -> WAR-safe); 12 reads -> counted lgkm(8)
            LD_A4(a, 0);
            LD_B2(b0, 0);
            if (t + 1 < NT) STAGE_HALF(t + 1, 1);
            asm volatile("s_waitcnt lgkmcnt(8)" ::: "memory");
            BARRIER;
            WAIT_LGKM0;
            __builtin_amdgcn_s_setprio(1);
            MFMA_QUAD(a, b0, 0, 0);
            __builtin_amdgcn_s_setprio(0);
            BARRIER;
            // ---- phase 2: quad (0,1); stage tile t+1 half2
            LD_B2(b1, 1);
            if (t + 1 < NT) STAGE_HALF(t + 1, 2);
            BARRIER;
            WAIT_LGKM0;
            __builtin_amdgcn_s_setprio(1);
            MFMA_QUAD(a, b1, 0, 1);
            __builtin_amdgcn_s_setprio(0);
            BARRIER;
            // ---- phase 3: quad (1,1); A1 time-shares a[]; stage tile t+1 half3
            LD_A4(a, 1);
            if (t + 1 < NT) STAGE_HALF(t + 1, 3);
            BARRIER;
            WAIT_LGKM0;                  // all reads of buf[p] now COMPLETE
            __builtin_amdgcn_s_setprio(1);
            MFMA_QUAD(a, b1, 1, 1);
            __builtin_amdgcn_s_setprio(0);
            BARRIER;                     // WAR fence: buf[p] free to overwrite
            // ---- phase 4: quad (1,0); stage tile t+2 half0 into buf[p];
            //      counted vmcnt(2): everything but the newest half landed
            if (t + 2 < NT) STAGE_HALF(t + 2, 0);
            BARRIER;
            __builtin_amdgcn_s_setprio(1);
            MFMA_QUAD(a, b0, 1, 0);
            __builtin_amdgcn_s_setprio(0);
            SBAR0;
            asm volatile("s_waitcnt vmcnt(2)" ::: "memory");
            __builtin_amdgcn_s_barrier();   // RAW: tile t+1 visible to all
            SBAR0;
        }
    }

    // C/D layout per 16x16 fragment: col = lane&15, row = (lane>>4)*4 + i
    // acc[am][an]: row = arow0+(am>>2)*64+(am&3)*16+q*4+i,
    //              col = brow0+(an>>1)*32+(an&1)*16+r
    if (MODE == 5) {
        float* C = (float*)Cv + (size_t)bz * sC;
#pragma unroll
        for (int am = 0; am < 8; ++am) {
            size_t row = bm + arow0 + (am >> 2) * 64 + (am & 3) * 16 + q * 4;
#pragma unroll
            for (int an = 0; an < 4; ++an) {
                size_t col = bn + brow0 + (an >> 1) * 32 + (an & 1) * 16 + r;
#pragma unroll
                for (int i = 0; i < 4; ++i)
                    C[(row + i) * (size_t)ldc + col] = acc[am][an][i];
            }
        }
    } else if (MODE == 4) {
        u16* C = (u16*)Cv + (size_t)bz * sC;
#pragma unroll
        for (int am = 0; am < 8; ++am) {
            size_t row = bm + arow0 + (am >> 2) * 64 + (am & 3) * 16 + q * 4;
#pragma unroll
            for (int an = 0; an < 4; ++an) {
                size_t col = bn + brow0 + (an >> 1) * 32 + (an & 1) * 16 + r;
#pragma unroll
                for (int i = 0; i < 4; ++i)
                    C[(row + i) * (size_t)ldc + col] = f2h(acc[am][an][i]);
            }
        }
    } else {  // MODE 3: fused QKV epilogue, region uniform per block
        int region = blockIdx.y >> 2;                 // 0:Q 1:K 2:V
        if (region < 2) {
            u16* C = (u16*)Cv + (size_t)region * 16777216;  // Q or K [16384x1024]
            size_t cb = bn - (size_t)region * 1024;
#pragma unroll
            for (int am = 0; am < 8; ++am) {
                size_t row = bm + arow0 + (am >> 2) * 64 + (am & 3) * 16 + q * 4;
#pragma unroll
                for (int an = 0; an < 4; ++an) {
                    size_t col = cb + brow0 + (an >> 1) * 32 + (an & 1) * 16 + r;
#pragma unroll
                    for (int i = 0; i < 4; ++i)
                        C[(row + i) * 1024 + col] = f2bf(acc[am][an][i]);
                }
            }
        } else {
            // VT[b][d][t] = V[b*2048+t][d]; b = bm>>11 is BLOCK-UNIFORM
            // (256-row tiles never straddle the 2048-row batch boundary).
            // Each lane owns 4 consecutive t at fixed d -> one ushort4 store.
            u16* Cb = (u16*)Cv2 + (bm >> 11) * (size_t)(1024 * 2048)
                      + (bn - 2048) * 2048 + (bm & 2047);
#pragma unroll
            for (int an = 0; an < 4; ++an) {
                int cI = brow0 + (an >> 1) * 32 + (an & 1) * 16 + r;
#pragma unroll
                for (int am = 0; am < 8; ++am) {
                    int tI = arow0 + (am >> 2) * 64 + (am & 3) * 16 + q * 4;
                    ushort4 o;
                    o.x = f2bf(acc[am][an][0]);
                    o.y = f2bf(acc[am][an][1]);
                    o.z = f2bf(acc[am][an][2]);
                    o.w = f2bf(acc[am][an][3]);
                    *(ushort4*)(Cb + (size_t)cI * 2048 + tI) = o;
                }
            }
        }
    }
}

// ---- masked softmax, ONE ROW PER WAVE: fp16 row in, bf16 P in place (full row)
// Read and write both use us8 chunks: chunk c = j*64+lane covers cols c*8..c*8+7.
__global__ void softmax_rows_w(u16* __restrict__ E, const int* __restrict__ lengths) {
    int row  = blockIdx.x * 4 + (threadIdx.x >> 6);   // 16384 rows, 4 waves/block
    int lane = threadIdx.x & 63;
    int len  = lengths[row >> 11];
    u16* e = E + (size_t)row * 2048;

    float vals[32];
#pragma unroll
    for (int j = 0; j < 4; ++j) {
        us8 v = ((const us8*)e)[j * 64 + lane];
#pragma unroll
        for (int w = 0; w < 8; ++w) vals[j * 8 + w] = h2f(v[w]);
    }

    float m = -3.4e38f;
#pragma unroll
    for (int j = 0; j < 4; ++j) {
        int base = (j * 64 + lane) * 8;
#pragma unroll
        for (int w = 0; w < 8; ++w)
            if (base + w < len) m = fmaxf(m, vals[j * 8 + w]);
    }
#pragma unroll
    for (int off = 32; off; off >>= 1) m = fmaxf(m, __shfl_xor(m, off));

    const float C = 0.18033688011112042f;   // log2(e)/8  (scale 1/sqrt(64))
    float p[32]; float s = 0.f;
#pragma unroll
    for (int j = 0; j < 4; ++j) {
        int base = (j * 64 + lane) * 8;
#pragma unroll
        for (int w = 0; w < 8; ++w) {
            float v = (base + w < len) ? exp2f((vals[j * 8 + w] - m) * C) : 0.f;
            p[j * 8 + w] = v;
            s += v;
        }
    }
#pragma unroll
    for (int off = 32; off; off >>= 1) s += __shfl_xor(s, off);
    float rinv = 1.0f / s;

    // bf16 P over the fp16 row, identical chunk mapping as the read
#pragma unroll
    for (int j = 0; j < 4; ++j) {
        us8 o;
#pragma unroll
        for (int w = 0; w < 8; ++w) o[w] = f2bf(p[j * 8 + w] * rinv);
        ((us8*)e)[j * 64 + lane] = o;
    }
}

// ------------------------------------------------------------------ launch
extern "C" void kernel_launch(void* const* d_in, const int* in_sizes, int n_in,
                              void* d_out, int out_size, void* d_ws, size_t ws_size,
                              hipStream_t stream) {
    const float* x  = (const float*)d_in[0];
    const float* Wq = (const float*)d_in[1];
    const float* Wk = (const float*)d_in[2];
    const float* Wv = (const float*)d_in[3];
    float* out = (float*)d_out;
    char* ws = (char*)d_ws;

    const size_t SB  = 2097152;      // u16 elems per batch [2048x1024]
    const size_t SBe = 4194304;      // u16 elems per batch energy [2048x2048]

    // ws: lengths 256B | x16 32MB | WT 6MB | VT 32MB | E 64MB fp16 = 140,509,440 B
    if (ws_size < 140509440ULL) return;
    int* lengths = (int*)ws;
    u16* x16 = (u16*)(ws + 256);
    u16* WT  = (u16*)(ws + 33554688);
    u16* VT  = (u16*)(ws + 39846144);
    u16* E   = (u16*)(ws + 73400576);
    u16* Qb  = (u16*)d_out;                          // Q,K parked in d_out (64 MiB)
    u16* Kb  = Qb + 16777216;

    cast_x<<<dim3(16384), dim3(256), 0, stream>>>(x, x16);
    transpose_cast_w<<<dim3(32, 32, 3), dim3(32, 8), 0, stream>>>(Wq, Wk, Wv, WT);
    calc_lengths<<<dim3(8), dim3(256), 0, stream>>>(x, lengths);

    // fused QKV: x16[16384x1024] @ WT[3072x1024]^T -> Q,K (d_out) + VT (ws)
    gemm_bt<3><<<dim3(64, 12, 1), 512, 0, stream>>>(x16, 1024, 0, WT, 1024, 0,
                                                    Qb, VT, 1024, 0, 1024, lengths);

    // energy[b] = Q_b K_b^T -> fp16 E; bn>=len skipped, bm>=len zero-filled
    gemm_bt<4><<<dim3(8, 8, 8), 512, 0, stream>>>(Qb, 1024, SB, Kb, 1024, SB,
                                                  E, nullptr, 2048, SBe, 1024, lengths);

    // masked softmax -> bf16 P in place (one row per wave)
    softmax_rows_w<<<dim3(4096), dim3(256), 0, stream>>>(E, lengths);

    // out[b] = P_b V_b = P_b (VT_b)^T; K clamped to round64(len[b])
    gemm_bt<5><<<dim3(8, 4, 8), 512, 0, stream>>>(E, 2048, SBe, VT, 2048, SB,
                                                  out, nullptr, 1024, SB, 2048, lengths);
}

// Round 7
// 374.471 us; speedup vs baseline: 1.1099x; 1.0214x over previous
//
#include <hip/hip_runtime.h>
#include <hip/hip_bf16.h>

// B=8, T=2048, E=1024, D=DK*H=1024 (heads fused in reference math)
//   QKV = x @ [Wq|Wk|Wv]  fused GEMM  [16384 x 3072] bf16 (V stored transposed);
//         m-blocks entirely beyond len[b] skip compute and store zeros.
//   energy[b] = Q_b K_b^T  fp16; n-blocks bn>=len skipped; m-blocks bm>=len
//         store exact zeros (Q rows are zero) without compute.
//   lengths[b] = #nonzero rows of x[b]
//   P = softmax(mask(energy)/8) bf16 in place over fp16 rows (one row per wave)
//   out[b] = P_b V_b  fp32; K-loop clamped to round64(len[b]).
//
// R15 (R6 corrected): R6 FAILED (absmax 1.97) because STAGE_T(t+2, buf p) was
// issued BEFORE tile t's ds_reads of the SAME buf p (t and t+2 share parity)
// -> staging writes raced the reads. Fix: stage moves after a mid-tile
// barrier that proves all waves drained their reads of buf[p]:
//   reads x16 (buf p) -> lgkm(8) -> MFMA(khalf0) -> lgkm(0) -> BARRIER#1
//   -> STAGE(t+2 -> buf p) -> MFMA(khalf1, from regs) -> vmcnt(8) [t+1
//   landed; tail: vmcnt(0)/none] -> BARRIER#2.
// Mechanisms kept from R14: 128x128 tile, BK=64, 4 waves (2x2), 64 KiB LDS
// dbuf -> TWO blocks/CU (launch_bounds(256,2)): two independent barrier
// domains per CU; one block's waves feed MFMA while the other waits.
// vmcnt ledger: outstanding = {t+1:8, t+2:8} -> vmcnt(8) == t+1 landed.
// ws = 140,509,440 B: lengths 256B | x16 32MB | WT 6MB | VT 32MB | E 64MB fp16.

typedef unsigned short u16;
typedef __bf16 bf16x8 __attribute__((ext_vector_type(8)));
typedef float f32x4 __attribute__((ext_vector_type(4)));
typedef unsigned short us8 __attribute__((ext_vector_type(8)));

__device__ __forceinline__ u16 f2bf(float f) {
    union { float f; unsigned u; } x; x.f = f;
    unsigned r = x.u + 0x7FFFu + ((x.u >> 16) & 1u);   // RNE
    return (u16)(r >> 16);
}
__device__ __forceinline__ u16 f2h(float f) {
    union { _Float16 h; u16 u; } c; c.h = (_Float16)f;
    return c.u;
}
__device__ __forceinline__ float h2f(u16 b) {
    union { u16 u; _Float16 h; } c; c.u = b;
    return (float)c.h;
}

__device__ __forceinline__ void gload_lds16(const void* g, void* l) {
    __builtin_amdgcn_global_load_lds(
        (const __attribute__((address_space(1))) unsigned*)g,
        (__attribute__((address_space(3))) unsigned*)l, 16, 0, 0);
}

// 32-bit LDS byte offset of a __shared__ object (addrspace(3) ptrs are 32-bit)
__device__ __forceinline__ unsigned lds_off(const void* p) {
    return (unsigned)(size_t)(const __attribute__((address_space(3))) char*)p;
}
// opaque LDS read: no alias edge to global_load_lds -> no compiler vmcnt drain
__device__ __forceinline__ bf16x8 ds_read16(unsigned a) {
    bf16x8 r;
    asm volatile("ds_read_b128 %0, %1" : "=v"(r) : "v"(a));
    return r;
}

// ---------------------------------------------------------------- cast x -> bf16
__global__ void cast_x(const float* __restrict__ x, u16* __restrict__ o) {
    int i = blockIdx.x * 256 + threadIdx.x;          // float4 index
    float4 v = ((const float4*)x)[i];
    ushort4 u;
    u.x = f2bf(v.x); u.y = f2bf(v.y); u.z = f2bf(v.z); u.w = f2bf(v.w);
    ((ushort4*)o)[i] = u;
}

// ------------------------------------------------- W[e][n] -> WT[n][e] bf16, x3
__global__ void transpose_cast_w(const float* __restrict__ Wq,
                                 const float* __restrict__ Wk,
                                 const float* __restrict__ Wv,
                                 u16* __restrict__ WT) {
    __shared__ float tile[32][33];
    const float* W = (blockIdx.z == 0) ? Wq : (blockIdx.z == 1) ? Wk : Wv;
    u16* T = WT + (size_t)blockIdx.z * 1048576;
    int n0 = blockIdx.x * 32, e0 = blockIdx.y * 32;
    int tx = threadIdx.x, ty = threadIdx.y;
#pragma unroll
    for (int j = 0; j < 4; ++j) {
        int e = ty + j * 8;
        tile[e][tx] = W[(size_t)(e0 + e) * 1024 + (n0 + tx)];
    }
    __syncthreads();
#pragma unroll
    for (int j = 0; j < 4; ++j) {
        int n = ty + j * 8;
        T[(size_t)(n0 + n) * 1024 + (e0 + tx)] = f2bf(tile[tx][n]);
    }
}

// ----------------------------------------------------- lengths[b] from x rows
__global__ void calc_lengths(const float* __restrict__ x, int* __restrict__ len) {
    int b = blockIdx.x, tid = threadIdx.x;
    int cnt = 0;
    for (int t = tid; t < 2048; t += 256) {
        float4 v = *(const float4*)(x + ((size_t)b * 2048 + t) * 1024);
        cnt += (v.x != 0.f || v.y != 0.f || v.z != 0.f || v.w != 0.f) ? 1 : 0;
    }
#pragma unroll
    for (int off = 32; off; off >>= 1) cnt += __shfl_xor(cnt, off);
    __shared__ int red[4];
    int wid = tid >> 6, lane = tid & 63;
    if (!lane) red[wid] = cnt;
    __syncthreads();
    if (tid == 0) len[b] = red[0] + red[1] + red[2] + red[3];
}

// ------------------------------------------------------------- bf16 NT GEMM
// 128x128 tile, BK=64, 2 barriers/K-tile, 2 blocks/CU. C[m,n]=sum_k A[m,k]B[n,k].
// MODE 3: fused-QKV routing (y 0-7 Q, 8-15 K, 16-23 V transposed into Cv2)
// MODE 4: energy fp16; n-blocks bn>=len return; m-blocks bm>=len store zeros
// MODE 5: PV fp32; K clamped to round64(len)

#define SBAR0 __builtin_amdgcn_sched_barrier(0)

#define STAGE_T(KT, BUF) do { \
  _Pragma("unroll") for (int j_ = 0; j_ < 4; ++j_) \
      gload_lds16(A + offA[j_] + (size_t)(KT) * 64, &As[BUF][ldsC[j_]]); \
  _Pragma("unroll") for (int j_ = 0; j_ < 4; ++j_) \
      gload_lds16(B + offB[j_] + (size_t)(KT) * 64, &Bs[BUF][ldsC[j_]]); \
} while (0)

#define LD_A(S) do { \
  _Pragma("unroll") for (int mt_ = 0; mt_ < 4; ++mt_) \
    af[S][mt_] = ds_read16(rowA[mt_] + ((S) ? ps1 : ps0)); \
} while (0)
#define LD_B(S) do { \
  _Pragma("unroll") for (int nt_ = 0; nt_ < 4; ++nt_) \
    bf[S][nt_] = ds_read16(rowB[nt_] + ((S) ? ps1 : ps0)); \
} while (0)

#define MFMA_S(S) do { \
  _Pragma("unroll") for (int mt_ = 0; mt_ < 4; ++mt_) \
  _Pragma("unroll") for (int nt_ = 0; nt_ < 4; ++nt_) \
    acc[mt_][nt_] = __builtin_amdgcn_mfma_f32_16x16x32_bf16( \
        af[S][mt_], bf[S][nt_], acc[mt_][nt_], 0, 0, 0); \
} while (0)

template <int MODE>
__global__ __launch_bounds__(256, 2)   // 4 waves; 2 blocks/CU (64 KiB LDS each)
void gemm_bt(const u16* __restrict__ A, int lda, size_t sA,
             const u16* __restrict__ B, int ldb, size_t sB,
             void* __restrict__ Cv, void* __restrict__ Cv2,
             int ldc, size_t sC, int Kdim, const int* __restrict__ lenp) {
    __shared__ u16 As[2][128 * 64];    // 32 KiB (16 KiB per parity buffer)
    __shared__ u16 Bs[2][128 * 64];    // 32 KiB
    const int tid = threadIdx.x;
    const int bz  = blockIdx.z;
    A += (size_t)bz * sA;
    B += (size_t)bz * sB;
    const size_t bm = (size_t)blockIdx.x * 128, bn = (size_t)blockIdx.y * 128;

    bool skip = false;
    int kEnd = Kdim;
    if (MODE == 3) {
        int lenz = lenp[bm >> 11];
        skip = ((int)(bm & 2047) >= lenz);           // whole tile rows are zero
    } else if (MODE == 4) {
        int lenz = lenp[bz];
        if ((int)bn >= lenz) return;                 // cols fully masked: unread
        skip = ((int)bm >= lenz);                    // Q rows zero -> energy 0
    } else if (MODE == 5) {
        int lenz = lenp[bz];
        int r64 = (lenz + 63) & ~63;
        kEnd = r64 < Kdim ? r64 : Kdim;              // P cols >= len are zeros
    }

    const int wid = tid >> 6, lane = tid & 63;
    const int wm = wid >> 1, wn = wid & 1;           // 2M x 2N wave grid
    const int q = lane >> 4, r = lane & 15;

    // staging: each matrix tile = 1024 x 16B chunks; thread owns c = j*256+tid.
    // chunk c -> linear LDS byte c*16 (wave-contiguous); global source column
    // pre-swizzled so LDS[linear] == swizzled layout (rule #21).
    size_t offA[4], offB[4]; int ldsC[4];
#pragma unroll
    for (int j = 0; j < 4; ++j) {
        int c = j * 256 + tid;
        int row = c >> 3;
        int c16 = (c & 7) ^ (row & 7);               // involution swizzle
        offA[j] = (size_t)(bm + row) * lda + c16 * 8;
        offB[j] = (size_t)(bn + row) * ldb + c16 * 8;
        ldsC[j] = c * 8;
    }

    // precomputed LDS read addresses (buf0): row base + swizzled 16B chunk
    unsigned rowA[4], rowB[4], swz0, swz1;
    {
        unsigned asB = lds_off(&As[0][0]), bsB = lds_off(&Bs[0][0]);
        swz0 = (unsigned)((q ^ (r & 7)) * 16);
        swz1 = (unsigned)(((q + 4) ^ (r & 7)) * 16);
#pragma unroll
        for (int mt = 0; mt < 4; ++mt)
            rowA[mt] = asB + (unsigned)((wm * 64 + mt * 16 + r) * 128);
#pragma unroll
        for (int nt = 0; nt < 4; ++nt)
            rowB[nt] = bsB + (unsigned)((wn * 64 + nt * 16 + r) * 128);
    }

    f32x4 acc[4][4] = {};

    if (!skip) {
        const int NT = kEnd >> 6;                    // >= 16 always (len>=1024)
        STAGE_T(0, 0);
        STAGE_T(1, 1);
        asm volatile("s_waitcnt vmcnt(8)" ::: "memory");   // tile 0 landed
        SBAR0; __builtin_amdgcn_s_barrier(); SBAR0;
        for (int t = 0; t < NT; ++t) {
            const int p = t & 1;
            const unsigned ps0 = (unsigned)(p << 14) + swz0;
            const unsigned ps1 = (unsigned)(p << 14) + swz1;
            bf16x8 af[2][4], bf[2][4];
            // 16 ds_reads of buf[p]: khalf0 (A,B) then khalf1 (A,B)
            LD_A(0); LD_B(0);
            LD_A(1); LD_B(1);
            asm volatile("s_waitcnt lgkmcnt(8)" ::: "memory");  // khalf0 ready
            SBAR0;
            __builtin_amdgcn_s_setprio(1);
            MFMA_S(0);                              // khalf1 lands underneath
            __builtin_amdgcn_s_setprio(0);
            SBAR0;
            asm volatile("s_waitcnt lgkmcnt(0)" ::: "memory");  // all reads done
            SBAR0;
            __builtin_amdgcn_s_barrier();           // #1: block-wide read drain
            SBAR0;
            // WAR-safe NOW: stage tile t+2 into buf[p]; overlaps MFMA_S(1)
            if (t + 2 < NT) STAGE_T(t + 2, p);
            SBAR0;
            __builtin_amdgcn_s_setprio(1);
            MFMA_S(1);                              // operands already in regs
            __builtin_amdgcn_s_setprio(0);
            SBAR0;
            // counted vmcnt: outstanding {t+1:8, t+2:8} -> 8 == t+1 landed
            if (t + 2 < NT)      asm volatile("s_waitcnt vmcnt(8)" ::: "memory");
            else if (t + 1 < NT) asm volatile("s_waitcnt vmcnt(0)" ::: "memory");
            __builtin_amdgcn_s_barrier();           // #2: tile t+1 visible to all
            SBAR0;
        }
    }

    // C/D layout per 16x16 fragment: col = lane&15, row = (lane>>4)*4 + i
    // acc[mt][nt]: row = wm*64 + mt*16 + q*4 + i, col = wn*64 + nt*16 + r
    if (MODE == 5) {
        float* C = (float*)Cv + (size_t)bz * sC;
#pragma unroll
        for (int mt = 0; mt < 4; ++mt) {
            size_t row = bm + wm * 64 + mt * 16 + q * 4;
#pragma unroll
            for (int nt = 0; nt < 4; ++nt) {
                size_t col = bn + wn * 64 + nt * 16 + r;
#pragma unroll
                for (int i = 0; i < 4; ++i)
                    C[(row + i) * (size_t)ldc + col] = acc[mt][nt][i];
            }
        }
    } else if (MODE == 4) {
        u16* C = (u16*)Cv + (size_t)bz * sC;
#pragma unroll
        for (int mt = 0; mt < 4; ++mt) {
            size_t row = bm + wm * 64 + mt * 16 + q * 4;
#pragma unroll
            for (int nt = 0; nt < 4; ++nt) {
                size_t col = bn + wn * 64 + nt * 16 + r;
#pragma unroll
                for (int i = 0; i < 4; ++i)
                    C[(row + i) * (size_t)ldc + col] = f2h(acc[mt][nt][i]);
            }
        }
    } else {  // MODE 3: fused QKV epilogue, region uniform per block
        int region = blockIdx.y >> 3;                 // 0:Q 1:K 2:V (8 y each)
        if (region < 2) {
            u16* C = (u16*)Cv + (size_t)region * 16777216;  // Q or K [16384x1024]
            size_t cb = bn - (size_t)region * 1024;
#pragma unroll
            for (int mt = 0; mt < 4; ++mt) {
                size_t row = bm + wm * 64 + mt * 16 + q * 4;
#pragma unroll
                for (int nt = 0; nt < 4; ++nt) {
                    size_t col = cb + wn * 64 + nt * 16 + r;
#pragma unroll
                    for (int i = 0; i < 4; ++i)
                        C[(row + i) * 1024 + col] = f2bf(acc[mt][nt][i]);
                }
            }
        } else {
            // VT[b][d][t] = V[b*2048+t][d]; b = bm>>11 is BLOCK-UNIFORM
            // (128-row tiles never straddle the 2048-row batch boundary).
            // Each lane owns 4 consecutive t at fixed d -> one ushort4 store.
            u16* Cb = (u16*)Cv2 + (bm >> 11) * (size_t)(1024 * 2048)
                      + (bn - 2048) * 2048 + (bm & 2047);
#pragma unroll
            for (int nt = 0; nt < 4; ++nt) {
                int cI = wn * 64 + nt * 16 + r;
#pragma unroll
                for (int mt = 0; mt < 4; ++mt) {
                    int tI = wm * 64 + mt * 16 + q * 4;
                    ushort4 o;
                    o.x = f2bf(acc[mt][nt][0]);
                    o.y = f2bf(acc[mt][nt][1]);
                    o.z = f2bf(acc[mt][nt][2]);
                    o.w = f2bf(acc[mt][nt][3]);
                    *(ushort4*)(Cb + (size_t)cI * 2048 + tI) = o;
                }
            }
        }
    }
}

// ---- masked softmax, ONE ROW PER WAVE: fp16 row in, bf16 P in place (full row)
// Read and write both use us8 chunks: chunk c = j*64+lane covers cols c*8..c*8+7.
__global__ void softmax_rows_w(u16* __restrict__ E, const int* __restrict__ lengths) {
    int row  = blockIdx.x * 4 + (threadIdx.x >> 6);   // 16384 rows, 4 waves/block
    int lane = threadIdx.x & 63;
    int len  = lengths[row >> 11];
    u16* e = E + (size_t)row * 2048;

    float vals[32];
#pragma unroll
    for (int j = 0; j < 4; ++j) {
        us8 v = ((const us8*)e)[j * 64 + lane];
#pragma unroll
        for (int w = 0; w < 8; ++w) vals[j * 8 + w] = h2f(v[w]);
    }

    float m = -3.4e38f;
#pragma unroll
    for (int j = 0; j < 4; ++j) {
        int base = (j * 64 + lane) * 8;
#pragma unroll
        for (int w = 0; w < 8; ++w)
            if (base + w < len) m = fmaxf(m, vals[j * 8 + w]);
    }
#pragma unroll
    for (int off = 32; off; off >>= 1) m = fmaxf(m, __shfl_xor(m, off));

    const float C = 0.18033688011112042f;   // log2(e)/8  (scale 1/sqrt(64))
    float p[32]; float s = 0.f;
#pragma unroll
    for (int j = 0; j < 4; ++j) {
        int base = (j * 64 + lane) * 8;
#pragma unroll
        for (int w = 0; w < 8; ++w) {
            float v = (base + w < len) ? exp2f((vals[j * 8 + w] - m) * C) : 0.f;
            p[j * 8 + w] = v;
            s += v;
        }
    }
#pragma unroll
    for (int off = 32; off; off >>= 1) s += __shfl_xor(s, off);
    float rinv = 1.0f / s;

    // bf16 P over the fp16 row, identical chunk mapping as the read
#pragma unroll
    for (int j = 0; j < 4; ++j) {
        us8 o;
#pragma unroll
        for (int w = 0; w < 8; ++w) o[w] = f2bf(p[j * 8 + w] * rinv);
        ((us8*)e)[j * 64 + lane] = o;
    }
}

// ------------------------------------------------------------------ launch
extern "C" void kernel_launch(void* const* d_in, const int* in_sizes, int n_in,
                              void* d_out, int out_size, void* d_ws, size_t ws_size,
                              hipStream_t stream) {
    const float* x  = (const float*)d_in[0];
    const float* Wq = (const float*)d_in[1];
    const float* Wk = (const float*)d_in[2];
    const float* Wv = (const float*)d_in[3];
    float* out = (float*)d_out;
    char* ws = (char*)d_ws;

    const size_t SB  = 2097152;      // u16 elems per batch [2048x1024]
    const size_t SBe = 4194304;      // u16 elems per batch energy [2048x2048]

    // ws: lengths 256B | x16 32MB | WT 6MB | VT 32MB | E 64MB fp16 = 140,509,440 B
    if (ws_size < 140509440ULL) return;
    int* lengths = (int*)ws;
    u16* x16 = (u16*)(ws + 256);
    u16* WT  = (u16*)(ws + 33554688);
    u16* VT  = (u16*)(ws + 39846144);
    u16* E   = (u16*)(ws + 73400576);
    u16* Qb  = (u16*)d_out;                          // Q,K parked in d_out (64 MiB)
    u16* Kb  = Qb + 16777216;

    cast_x<<<dim3(16384), dim3(256), 0, stream>>>(x, x16);
    transpose_cast_w<<<dim3(32, 32, 3), dim3(32, 8), 0, stream>>>(Wq, Wk, Wv, WT);
    calc_lengths<<<dim3(8), dim3(256), 0, stream>>>(x, lengths);

    // fused QKV: x16[16384x1024] @ WT[3072x1024]^T -> Q,K (d_out) + VT (ws)
    gemm_bt<3><<<dim3(128, 24, 1), 256, 0, stream>>>(x16, 1024, 0, WT, 1024, 0,
                                                     Qb, VT, 1024, 0, 1024, lengths);

    // energy[b] = Q_b K_b^T -> fp16 E; bn>=len skipped, bm>=len zero-filled
    gemm_bt<4><<<dim3(16, 16, 8), 256, 0, stream>>>(Qb, 1024, SB, Kb, 1024, SB,
                                                    E, nullptr, 2048, SBe, 1024, lengths);

    // masked softmax -> bf16 P in place (one row per wave)
    softmax_rows_w<<<dim3(4096), dim3(256), 0, stream>>>(E, lengths);

    // out[b] = P_b V_b = P_b (VT_b)^T; K clamped to round64(len[b])
    gemm_bt<5><<<dim3(16, 8, 8), 256, 0, stream>>>(E, 2048, SBe, VT, 2048, SB,
                                                   out, nullptr, 1024, SB, 2048, lengths);
}